// Round 13
// baseline (483.717 us; speedup 1.0000x reference)
//
#include <hip/hip_runtime.h>
#include <math.h>

#define CDIV(a, b) (((a) + (b) - 1) / (b))

#define LOG2E 1.4426950408889634f
#define SC5  (0.44721359549996f * LOG2E)
#define SC10 (0.31622776601684f * LOG2E)
#define SC21 (0.21821789023599f * LOG2E)
#define EXP2(x) __builtin_amdgcn_exp2f(x)

template <int N> __device__ inline void waitcnt_vm() {
    if constexpr (N == 0) asm volatile("s_waitcnt vmcnt(0)" ::: "memory");
    else if constexpr (N == 3) asm volatile("s_waitcnt vmcnt(3)" ::: "memory");
    else static_assert(N < 0, "unsupported vmcnt literal");
}

// ---------- fused 3x3 s2 conv + relu + qkv projection (layer 1 only) ----------
// zt stored TRANSPOSED+padded [px][COUT+4] so phase-2 reads are float4 LDS loads.
template <int CIN, int HIN, int COUT, int HOUT, int INNER, int DP, int KVRS, int KVD, int TPX,
          int BS>
__global__ void __launch_bounds__(BS) conv_qkv(const float* __restrict__ in,
                                               const float* __restrict__ cw,
                                               const float* __restrict__ cb,
                                               const float* __restrict__ qw,
                                               const float* __restrict__ qb,
                                               float* __restrict__ z, float* __restrict__ q,
                                               float* __restrict__ kv) {
    constexpr int N = HOUT * HOUT;
    constexpr int ZSTR = COUT + 4;          // pad: bank spread + keeps 16B alignment
    __shared__ float zt[TPX * ZSTR];
    const int b  = blockIdx.x / (N / TPX);
    const int n0 = (blockIdx.x % (N / TPX)) * TPX;
    const int tid = threadIdx.x;

    for (int idx = tid; idx < COUT * TPX; idx += BS) {
        int c = idx / TPX, px = idx % TPX;
        int n = n0 + px;
        int ho = n / HOUT, wo = n % HOUT;
        float a0 = cb[c], a1 = 0.f, a2 = 0.f;     // 3-way ILP over kh
        for (int ci = 0; ci < CIN; ++ci) {
            const float* ip = in + (size_t)(b * CIN + ci) * HIN * HIN;
            const float* wp = cw + (size_t)(c * CIN + ci) * 9;
            #pragma unroll
            for (int kh = 0; kh < 3; ++kh) {
                int hi = 2 * ho + kh - 1;
                if (hi < 0 || hi >= HIN) continue;
                float av = 0.f;
                #pragma unroll
                for (int kw = 0; kw < 3; ++kw) {
                    int wi = 2 * wo + kw - 1;
                    if (wi < 0 || wi >= HIN) continue;
                    av = fmaf(wp[kh * 3 + kw], ip[hi * HIN + wi], av);
                }
                if (kh == 0) a0 += av; else if (kh == 1) a1 += av; else a2 += av;
            }
        }
        float acc = fmaxf((a0 + a1) + a2, 0.f);
        zt[px * ZSTR + c] = acc;
        z[((size_t)(b * COUT) + c) * N + n] = acc;
    }
    __syncthreads();

    constexpr int OC3 = 3 * INNER;
    constexpr int NF4 = COUT / 4;
    for (int idx = tid; idx < OC3 * TPX; idx += BS) {
        int oc = idx / TPX, px = idx % TPX;
        const float4* wp4 = (const float4*)(qw + (size_t)oc * COUT);
        const float4* z4  = (const float4*)(zt + px * ZSTR);
        float vs[4] = {0.f, 0.f, 0.f, 0.f};
        #pragma unroll
        for (int c4 = 0; c4 < NF4; ++c4) {
            float4 a = wp4[c4], bb = z4[c4];
            float& v = vs[c4 & 3];
            v = fmaf(a.x, bb.x, v); v = fmaf(a.y, bb.y, v);
            v = fmaf(a.z, bb.z, v); v = fmaf(a.w, bb.w, v);
        }
        float val = qb[oc] + ((vs[0] + vs[1]) + (vs[2] + vs[3]));
        int part = oc / INNER;
        int r = oc - part * INNER;
        int hh = r % 3, dd = r / 3;  // heads fastest
        size_t n = n0 + px;
        if (part == 0)
            q[((size_t)(b * 3 + hh) * N + n) * DP + dd] = val;
        else
            kv[((size_t)(b * 3 + hh) * N + n) * KVRS + (part - 1) * KVD + dd] = val;
    }
}

// ---------- fused: prev outproj(+residual) halo -> conv3x3 s2 relu -> qkv ----------
template <int CPREV, int INNERP, int DPREV, int HINW, int COUT, int HOUT, int INNER, int DP,
          int KVRS, int KVD, int TPX, int BS>
__global__ void __launch_bounds__(BS) fused_oc(const float* __restrict__ o1,
                                               const float* __restrict__ ow,
                                               const float* __restrict__ ob,
                                               const float* __restrict__ zres,
                                               const float* __restrict__ cw,
                                               const float* __restrict__ cb,
                                               const float* __restrict__ qw,
                                               const float* __restrict__ qb,
                                               float* __restrict__ z, float* __restrict__ q,
                                               float* __restrict__ kv) {
    constexpr int N2 = HOUT * HOUT;
    constexpr int N1 = HINW * HINW;
    constexpr int TROWS = TPX / HOUT;     // output rows per tile
    constexpr int HR = 2 * TROWS + 1;     // halo input rows
    constexpr int HALO = HR * HINW;
    constexpr int ZSTR = COUT + 4;
    __shared__ float smem[INNERP * HALO + CPREV * HALO];
    float* o1s = smem;                    // INNERP*HALO (phase 0 only)
    float* zh  = smem + INNERP * HALO;    // CPREV*HALO
    float* zt  = smem;                    // TPX*ZSTR, overlays o1s after phase 0b
    static_assert(TPX * ZSTR <= INNERP * HALO, "zt overlay fits");
    const int b  = blockIdx.x / (N2 / TPX);
    const int n0 = (blockIdx.x % (N2 / TPX)) * TPX;
    const int tid = threadIdx.x;
    const int ho0 = n0 / HOUT;
    const int row0 = 2 * ho0 - 1;

    // phase 0a: stage o1 halo slice (coalesced)
    for (int t = tid; t < INNERP * HALO; t += BS) {
        int hd = t / HALO, p = t - hd * HALO;
        int row = row0 + p / HINW;
        float v = 0.f;
        if (row >= 0 && row < HINW)
            v = o1[((size_t)(b * INNERP + hd)) * N1 + row * HINW + (p % HINW)];
        o1s[t] = v;
    }
    __syncthreads();

    // phase 0b: outproj + bias + residual for the halo -> zh (3-way ILP over hh)
    for (int t = tid; t < CPREV * HALO; t += BS) {
        int ci = t / HALO, p = t - ci * HALO;
        int row = row0 + p / HINW;
        float val = 0.f;  // conv zero-padding
        if (row >= 0 && row < HINW) {
            int n1 = row * HINW + (p % HINW);
            const float* wp = ow + (size_t)ci * INNERP;
            float v0 = 0.f, v1 = 0.f, v2 = 0.f;
            for (int dd = 0; dd < DPREV; ++dd) {
                v0 = fmaf(wp[dd * 3 + 0], o1s[(0 * DPREV + dd) * HALO + p], v0);
                v1 = fmaf(wp[dd * 3 + 1], o1s[(1 * DPREV + dd) * HALO + p], v1);
                v2 = fmaf(wp[dd * 3 + 2], o1s[(2 * DPREV + dd) * HALO + p], v2);
            }
            val = ob[ci] + zres[((size_t)(b * CPREV) + ci) * N1 + n1] + (v0 + v1) + v2;
        }
        zh[t] = val;
    }
    __syncthreads();

    // phase 1: conv from LDS halo (+ relu); 3-way ILP over kh; zt transposed+padded
    for (int idx = tid; idx < COUT * TPX; idx += BS) {
        int c = idx / TPX, px = idx - (idx / TPX) * TPX;
        int hol = px / HOUT, wo = px - hol * HOUT;
        float a0 = cb[c], a1 = 0.f, a2 = 0.f;
        for (int ci = 0; ci < CPREV; ++ci) {
            const float* zp = zh + ci * HALO + (2 * hol) * HINW;
            const float* wp = cw + (size_t)(c * CPREV + ci) * 9;
            #pragma unroll
            for (int kw = 0; kw < 3; ++kw) {
                int col = 2 * wo + kw - 1;
                if (col < 0 || col >= HINW) continue;
                a0 = fmaf(wp[0 * 3 + kw], zp[0 * HINW + col], a0);
                a1 = fmaf(wp[1 * 3 + kw], zp[1 * HINW + col], a1);
                a2 = fmaf(wp[2 * 3 + kw], zp[2 * HINW + col], a2);
            }
        }
        float acc = fmaxf((a0 + a1) + a2, 0.f);
        zt[px * ZSTR + c] = acc;
        z[((size_t)(b * COUT) + c) * N2 + n0 + px] = acc;
    }
    __syncthreads();

    // phase 2: qkv from LDS tile (float4 LDS reads + 4 partial accumulators)
    constexpr int OC3 = 3 * INNER;
    constexpr int NF4 = COUT / 4;
    for (int idx = tid; idx < OC3 * TPX; idx += BS) {
        int oc = idx / TPX, px = idx % TPX;
        const float4* wp4 = (const float4*)(qw + (size_t)oc * COUT);
        const float4* z4  = (const float4*)(zt + px * ZSTR);
        float vs[4] = {0.f, 0.f, 0.f, 0.f};
        #pragma unroll
        for (int c4 = 0; c4 < NF4; ++c4) {
            float4 a = wp4[c4], bb = z4[c4];
            float& v = vs[c4 & 3];
            v = fmaf(a.x, bb.x, v); v = fmaf(a.y, bb.y, v);
            v = fmaf(a.z, bb.z, v); v = fmaf(a.w, bb.w, v);
        }
        float val = qb[oc] + ((vs[0] + vs[1]) + (vs[2] + vs[3]));
        int part = oc / INNER;
        int r = oc - part * INNER;
        int hh = r % 3, dd = r / 3;  // heads fastest
        size_t n = n0 + px;
        if (part == 0)
            q[((size_t)(b * 3 + hh) * N2 + n) * DP + dd] = val;
        else
            kv[((size_t)(b * 3 + hh) * N2 + n) * KVRS + (part - 1) * KVD + dd] = val;
    }
}

// ---------- attention (L1/L2): R6 staging + 2-STREAM accumulators ----------
// KV staged by global_load_lds DMA into wave-private LDS double-buffer; j-loop reads K/V
// via conflict-free LDS broadcasts. NEW vs R11: each wave runs TWO independent accumulation
// streams (j and j+TILE/2 within the SAME resident tile) -> 4 independent exp/FMA chains
// (2 rows x 2 streams) instead of 2, breaking the accumulator serialization that left
// ~22us of stall at 67% VALUBusy. No LDS/layout change; all indices compile-time.
template <int D, int QP, int RS, int RPT, int TILE, int NW>
__global__ void __launch_bounds__(NW * 64) attn_big(const float* __restrict__ q,
                                                    const float* __restrict__ kv,
                                                    const float* __restrict__ table,
                                                    float* __restrict__ o, int N, int log2Hg,
                                                    int T, float scale2) {
    extern __shared__ float smem[];
    float* tb = smem;       // T floats, pre-scaled by scale2 (incl. log2e)
    float* comb = smem;     // overlays tb + kv tiles after j-loop
    constexpr int BT = NW * 64;
    constexpr int ROWS = 64 * RPT;
    constexpr int CSTR = (D % 2 == 0) ? (D + 3) : (D + 2);
    constexpr int HT = TILE / 2;
    constexpr int TBYTES = TILE * RS * 4;          // bytes per tile
    constexpr int LPT = CDIV(TBYTES, 1024);        // global_load_lds calls per tile
    constexpr bool FULLT = (TBYTES % 1024) == 0;
    static_assert(LPT == 3, "vmcnt literal below assumes 3 loads per tile");

    const int bh = blockIdx.x % 96;
    const int chunk = blockIdx.x / 96;
    const int h = bh % 3;
    const int tid = threadIdx.x;
    const int wave = tid >> 6;
    const int lane = tid & 63;
    const int Hg = 1 << log2Hg;
    const int W2 = 2 * Hg - 1;
    const int base = chunk * ROWS;

    // wave-private KV tile double-buffer (16B-aligned offset past tb)
    float* kvw = smem + ((T + 3) & ~3) + wave * (2 * TILE * RS);

    for (int t = tid; t < T; t += BT) tb[t] = table[t * 3 + h] * scale2;

    float qr[RPT][D];
    const float* tbp[RPT];  // per-lane bias row base: tb + ibase[r]
    #pragma unroll
    for (int r = 0; r < RPT; ++r) {
        int i = base + lane + 64 * r;
        const float* qg = q + ((size_t)bh * N + i) * QP;
        #pragma unroll
        for (int dd = 0; dd < D; ++dd) qr[r][dd] = qg[dd];
        tbp[r] = tb + (((i >> log2Hg) + Hg - 1) * W2 + (i & (Hg - 1)) + Hg - 1);
    }

    float acc[2][RPT][D];
    float lsum[2][RPT];
    #pragma unroll
    for (int st = 0; st < 2; ++st)
        #pragma unroll
        for (int r = 0; r < RPT; ++r) {
            lsum[st][r] = 0.f;
            #pragma unroll
            for (int dd = 0; dd < D; ++dd) acc[st][r][dd] = 0.f;
        }

    const float* kvbase = kv + (size_t)bh * N * RS;
    const int NJ = N / NW;
    const int NT = NJ / TILE;
    const int j0 = wave * NJ;

    // DMA one tile into LDS buffer bufIdx (wave-uniform LDS base + lane*16 linear)
    auto stage = [&](int bufIdx, int t) {
        const float* srcf = kvbase + (size_t)(j0 + t * TILE) * RS;
        float* dstf = kvw + bufIdx * (TILE * RS);
        #pragma unroll
        for (int x = 0; x < LPT; ++x) {
            if (FULLT || (x * 1024 + lane * 16) < TBYTES) {
                const void* g = (const void*)(srcf + x * 256 + lane * 4);
                void* l = (void*)(dstf + x * 256);
                __builtin_amdgcn_global_load_lds(
                    (const __attribute__((address_space(1))) void*)g,
                    (__attribute__((address_space(3))) void*)l, 16, 0, 0);
            }
        }
    };

    // prologue: stage tiles 0 and 1; the tb barrier below drains them (vmcnt(0))
    stage(0, 0);
    if (NT > 1) stage(1, 1);

    __syncthreads();  // tb staged + prologue DMA complete

    for (int t = 0; t < NT; ++t) {
        const float* curb = kvw + (t & 1) * (TILE * RS);
        const int jt = j0 + t * TILE;
        for (int jg = 0; jg < HT; jg += 4) {
            #pragma unroll
            for (int k = 0; k < 4; ++k) {
                #pragma unroll
                for (int st = 0; st < 2; ++st) {
                    const int jj = jg + k + st * HT;     // compile-time stream offset
                    const int j = jt + jj;
                    const float* kr = curb + jj * RS;    // wave-uniform LDS broadcast
                    const int joff = (j >> log2Hg) * W2 + (j & (Hg - 1));
                    #pragma unroll
                    for (int r = 0; r < RPT; ++r) {
                        float s = 0.f;
                        #pragma unroll
                        for (int dd = 0; dd < D; ++dd) s = fmaf(qr[r][dd], kr[dd], s);
                        float e = EXP2(fmaf(s, scale2, tbp[r][-joff]));
                        lsum[st][r] += e;
                        #pragma unroll
                        for (int dd = 0; dd < D; ++dd)
                            acc[st][r][dd] = fmaf(e, kr[D + dd], acc[st][r][dd]);
                    }
                }
            }
        }
        if (t + 2 < NT) {
            // all reads of buf[t&1] done (DS in-order) before DMA may overwrite it
            asm volatile("s_waitcnt lgkmcnt(0)" ::: "memory");
            stage(t & 1, t + 2);
            waitcnt_vm<3>();   // tile t+1 resident; tile t+2's 3 loads stay in flight
        } else if (t + 1 < NT) {
            waitcnt_vm<0>();   // last tile: drain
        }
    }

    // merge the 2 streams
    #pragma unroll
    for (int r = 0; r < RPT; ++r) {
        lsum[0][r] += lsum[1][r];
        #pragma unroll
        for (int dd = 0; dd < D; ++dd) acc[0][r][dd] += acc[1][r][dd];
    }

    __syncthreads();
    #pragma unroll
    for (int r = 0; r < RPT; ++r) {
        float* cp = comb + (size_t)(wave * ROWS + lane + 64 * r) * CSTR;
        #pragma unroll
        for (int dd = 0; dd < D; ++dd) cp[dd] = acc[0][r][dd];
        cp[D] = lsum[0][r];
    }
    __syncthreads();
    if (tid < ROWS) {
        float af[D];
        #pragma unroll
        for (int dd = 0; dd < D; ++dd) af[dd] = 0.f;
        float lf = 0.f;
        #pragma unroll
        for (int wv = 0; wv < NW; ++wv) {
            const float* cp = comb + (size_t)(wv * ROWS + tid) * CSTR;
            #pragma unroll
            for (int dd = 0; dd < D; ++dd) af[dd] += cp[dd];
            lf += cp[D];
        }
        float inv = 1.0f / lf;
        int i = base + tid;
        #pragma unroll
        for (int dd = 0; dd < D; ++dd)
            o[((size_t)bh * D + dd) * N + i] = af[dd] * inv;  // O layout [bh][d][N]
    }
}

// ---------- L3 attention: one block per bh; KV+table staged in LDS; 8-wave j-split ----------
__global__ void __launch_bounds__(512) attn_small(const float* __restrict__ q,
                                                  const float* __restrict__ kv,
                                                  const float* __restrict__ table,
                                                  float* __restrict__ o, float scale2) {
    constexpr int D = 21, DP = 24, NN = 64;
    constexpr int CSTR = 23;
    __shared__ float smem[8 * NN * CSTR];  // 47104 B; comb overlays kvs/tb
    float* kvs = smem;
    float* tb = kvs + NN * 2 * DP;
    float* comb = smem;

    const int bh = blockIdx.x;     // 96 blocks
    const int h = bh % 3;
    const int tid = threadIdx.x;
    const int wave = tid >> 6;
    const int lane = tid & 63;

    {
        const float4* kvg = (const float4*)(kv + (size_t)bh * NN * 2 * DP);
        float4* kvs4 = (float4*)kvs;
        for (int t = tid; t < NN * 2 * DP / 4; t += 512) kvs4[t] = kvg[t];
        for (int t = tid; t < 225; t += 512) tb[t] = table[t * 3 + h] * scale2;
    }

    const int i = lane;
    const float* qg = q + ((size_t)bh * NN + i) * DP;
    float qr[D];
    #pragma unroll
    for (int dd = 0; dd < D; ++dd) qr[dd] = qg[dd];
    const int ibase = ((i >> 3) + 7) * 15 + (i & 7) + 7;
    __syncthreads();

    float acc[D];
    #pragma unroll
    for (int dd = 0; dd < D; ++dd) acc[dd] = 0.f;
    float lsum = 0.f;

    const int j0 = wave * 8;   // 8 waves x 8 js
    #pragma unroll
    for (int jj = 0; jj < 8; ++jj) {
        const int j = j0 + jj;
        float4 r4[12];
        const float4* rp = (const float4*)(kvs + j * 2 * DP);
        #pragma unroll
        for (int x = 0; x < 12; ++x) r4[x] = rp[x];
        const float* kr = (const float*)r4;
        const float* vr = kr + DP;
        const int joff = (j >> 3) * 15 + (j & 7);
        float s = 0.f;
        #pragma unroll
        for (int dd = 0; dd < D; ++dd) s = fmaf(qr[dd], kr[dd], s);
        float e = EXP2(fmaf(s, scale2, tb[ibase - joff]));
        lsum += e;
        #pragma unroll
        for (int dd = 0; dd < D; ++dd) acc[dd] = fmaf(e, vr[dd], acc[dd]);
    }

    __syncthreads();
    {
        float* cp = comb + (size_t)(wave * NN + lane) * CSTR;
        #pragma unroll
        for (int dd = 0; dd < D; ++dd) cp[dd] = acc[dd];
        cp[D] = lsum;
    }
    __syncthreads();
    if (tid < NN) {
        float af[D];
        #pragma unroll
        for (int dd = 0; dd < D; ++dd) af[dd] = 0.f;
        float lf = 0.f;
        #pragma unroll
        for (int wv = 0; wv < 8; ++wv) {
            const float* cp = comb + (size_t)(wv * NN + tid) * CSTR;
            #pragma unroll
            for (int dd = 0; dd < D; ++dd) af[dd] += cp[dd];
            lf += cp[D];
        }
        float inv = 1.0f / lf;
        #pragma unroll
        for (int dd = 0; dd < D; ++dd)
            o[((size_t)bh * D + dd) * NN + tid] = af[dd] * inv;
    }
}

// ---------- tail: outproj3 + global-avg-pool + classifier (3-way ILP over hh) ----------
__global__ void __launch_bounds__(256) tail(const float* __restrict__ o,
                                            const float* __restrict__ ow,
                                            const float* __restrict__ ob,
                                            const float* __restrict__ zin,
                                            const float* __restrict__ cw,
                                            const float* __restrict__ cb,
                                            float* __restrict__ out) {
    __shared__ float os[63 * 64];
    __shared__ float zt[64 * 65];
    __shared__ float p[64];
    const int b = blockIdx.x;
    const int tid = threadIdx.x;
    // stage o[b]: rows b*63..b*63+62 are contiguous (layout [bh][d][N], hd = hh*21+dd)
    for (int t = tid; t < 63 * 64; t += 256) os[t] = o[(size_t)(b * 63) * 64 + t];
    __syncthreads();
    for (int idx = tid; idx < 64 * 64; idx += 256) {
        int c = idx >> 6, n = idx & 63;
        const float* wp = ow + (size_t)c * 63;
        float v0 = 0.f, v1 = 0.f, v2 = 0.f;
        for (int dd = 0; dd < 21; ++dd) {
            v0 = fmaf(wp[dd * 3 + 0], os[(0  + dd) * 64 + n], v0);
            v1 = fmaf(wp[dd * 3 + 1], os[(21 + dd) * 64 + n], v1);
            v2 = fmaf(wp[dd * 3 + 2], os[(42 + dd) * 64 + n], v2);
        }
        zt[c * 65 + n] = ob[c] + zin[((size_t)(b * 64) + c) * 64 + n] + (v0 + v1) + v2;
    }
    __syncthreads();
    if (tid < 64) {
        float s = 0.f;
        #pragma unroll
        for (int n = 0; n < 64; ++n) s += zt[tid * 65 + n];
        s *= (1.0f / 64.0f);
        p[tid] = s;
        out[b * 64 + tid] = s;
    }
    __syncthreads();
    if (tid < 10) {
        float val = cb[tid];
        const float* wp = cw + (size_t)tid * 64;
        #pragma unroll
        for (int kk = 0; kk < 64; ++kk) val = fmaf(wp[kk], p[kk], val);
        out[2048 + b * 10 + tid] = val;
    }
}

extern "C" void kernel_launch(void* const* d_in, const int* in_sizes, int n_in,
                              void* d_out, int out_size, void* d_ws, size_t ws_size,
                              hipStream_t stream) {
    float* ws = (float*)d_ws;
    float* Zc1 = ws;                 // conv1 z (524288) / later conv3 z (131072)
    float* Zc2 = Zc1 + 524288;       // conv2 z (262144)
    float* Q   = Zc2 + 262144;       // 786432 (96*1024*8 max)
    float* KV  = Q + 786432;         // 1572864 region (L1 packed uses 96*1024*12)
    float* O   = KV + 1572864;       // 491520 (96*1024*5 max)

    float* out = (float*)d_out;

    // ===== layer 1: Cin=1 H64->32, dim=16, inner=15, d=5 (q pad 8, kv stride 12), N=1024 =====
    conv_qkv<1, 64, 16, 32, 15, 8, 12, 5, 32, 512><<<32 * 32, 512, 0, stream>>>(
        (const float*)d_in[0], (const float*)d_in[1], (const float*)d_in[2],
        (const float*)d_in[3], (const float*)d_in[4], Zc1, Q, KV);
    // R6 shape (RPT=2, NW=4, TILE=64, 768 blocks) + 2-stream accumulators
    attn_big<5, 8, 12, 2, 64, 4><<<96 * 8, 256, 40464, stream>>>(
        Q, KV, (const float*)d_in[7], O, 1024, 5, 3969, SC5);

    // ===== layer 2 (fused outproj1 + conv2 + qkv2): dim=32, d=10 (q pad 12, kv stride 20), N=256 =====
    fused_oc<16, 15, 5, 32, 32, 16, 30, 12, 20, 10, 16, 512><<<32 * 16, 512, 0, stream>>>(
        O, (const float*)d_in[5], (const float*)d_in[6], Zc1,
        (const float*)d_in[8], (const float*)d_in[9],
        (const float*)d_in[10], (const float*)d_in[11], Zc2, Q, KV);
    // NW=8, RPT=1, TILE=32 (NT=1), 2-stream; smem = (964 + 8*2*32*20)*4 = 44816 B
    attn_big<10, 12, 20, 1, 32, 8><<<96 * 4, 512, 44816, stream>>>(
        Q, KV, (const float*)d_in[14], O, 256, 4, 961, SC10);

    // ===== layer 3 (fused outproj2 + conv3 + qkv3): dim=64, d=21 (DP=24, kv interleaved 48) =====
    fused_oc<32, 30, 10, 16, 64, 8, 63, 24, 48, 24, 8, 512><<<32 * 8, 512, 0, stream>>>(
        O, (const float*)d_in[12], (const float*)d_in[13], Zc2,
        (const float*)d_in[15], (const float*)d_in[16],
        (const float*)d_in[17], (const float*)d_in[18], Zc1, Q, KV);
    attn_small<<<96, 512, 0, stream>>>(Q, KV, (const float*)d_in[21], O, SC21);

    // ===== head =====
    tail<<<32, 256, 0, stream>>>(
        O, (const float*)d_in[19], (const float*)d_in[20], Zc1,
        (const float*)d_in[22], (const float*)d_in[23], out);
}

// Round 14
// 249.280 us; speedup vs baseline: 1.9405x; 1.9405x over previous
//
#include <hip/hip_runtime.h>
#include <math.h>

#define CDIV(a, b) (((a) + (b) - 1) / (b))

#define LOG2E 1.4426950408889634f
#define SC5  (0.44721359549996f * LOG2E)
#define SC10 (0.31622776601684f * LOG2E)
#define SC21 (0.21821789023599f * LOG2E)
#define EXP2(x) __builtin_amdgcn_exp2f(x)

template <int N> __device__ inline void waitcnt_vm() {
    if constexpr (N == 0) asm volatile("s_waitcnt vmcnt(0)" ::: "memory");
    else if constexpr (N == 3) asm volatile("s_waitcnt vmcnt(3)" ::: "memory");
    else static_assert(N < 0, "unsupported vmcnt literal");
}

// ---------- fused 3x3 s2 conv + relu + qkv projection (layer 1 only) ----------
// zt stored TRANSPOSED+padded [px][COUT+4] so phase-2 reads are float4 LDS loads.
template <int CIN, int HIN, int COUT, int HOUT, int INNER, int DP, int KVRS, int KVD, int TPX,
          int BS>
__global__ void __launch_bounds__(BS) conv_qkv(const float* __restrict__ in,
                                               const float* __restrict__ cw,
                                               const float* __restrict__ cb,
                                               const float* __restrict__ qw,
                                               const float* __restrict__ qb,
                                               float* __restrict__ z, float* __restrict__ q,
                                               float* __restrict__ kv) {
    constexpr int N = HOUT * HOUT;
    constexpr int ZSTR = COUT + 4;          // pad: bank spread + keeps 16B alignment
    __shared__ float zt[TPX * ZSTR];
    const int b  = blockIdx.x / (N / TPX);
    const int n0 = (blockIdx.x % (N / TPX)) * TPX;
    const int tid = threadIdx.x;

    for (int idx = tid; idx < COUT * TPX; idx += BS) {
        int c = idx / TPX, px = idx % TPX;
        int n = n0 + px;
        int ho = n / HOUT, wo = n % HOUT;
        float a0 = cb[c], a1 = 0.f, a2 = 0.f;     // 3-way ILP over kh
        for (int ci = 0; ci < CIN; ++ci) {
            const float* ip = in + (size_t)(b * CIN + ci) * HIN * HIN;
            const float* wp = cw + (size_t)(c * CIN + ci) * 9;
            #pragma unroll
            for (int kh = 0; kh < 3; ++kh) {
                int hi = 2 * ho + kh - 1;
                if (hi < 0 || hi >= HIN) continue;
                float av = 0.f;
                #pragma unroll
                for (int kw = 0; kw < 3; ++kw) {
                    int wi = 2 * wo + kw - 1;
                    if (wi < 0 || wi >= HIN) continue;
                    av = fmaf(wp[kh * 3 + kw], ip[hi * HIN + wi], av);
                }
                if (kh == 0) a0 += av; else if (kh == 1) a1 += av; else a2 += av;
            }
        }
        float acc = fmaxf((a0 + a1) + a2, 0.f);
        zt[px * ZSTR + c] = acc;
        z[((size_t)(b * COUT) + c) * N + n] = acc;
    }
    __syncthreads();

    constexpr int OC3 = 3 * INNER;
    constexpr int NF4 = COUT / 4;
    for (int idx = tid; idx < OC3 * TPX; idx += BS) {
        int oc = idx / TPX, px = idx % TPX;
        const float4* wp4 = (const float4*)(qw + (size_t)oc * COUT);
        const float4* z4  = (const float4*)(zt + px * ZSTR);
        float vs[4] = {0.f, 0.f, 0.f, 0.f};
        #pragma unroll
        for (int c4 = 0; c4 < NF4; ++c4) {
            float4 a = wp4[c4], bb = z4[c4];
            float& v = vs[c4 & 3];
            v = fmaf(a.x, bb.x, v); v = fmaf(a.y, bb.y, v);
            v = fmaf(a.z, bb.z, v); v = fmaf(a.w, bb.w, v);
        }
        float val = qb[oc] + ((vs[0] + vs[1]) + (vs[2] + vs[3]));
        int part = oc / INNER;
        int r = oc - part * INNER;
        int hh = r % 3, dd = r / 3;  // heads fastest
        size_t n = n0 + px;
        if (part == 0)
            q[((size_t)(b * 3 + hh) * N + n) * DP + dd] = val;
        else
            kv[((size_t)(b * 3 + hh) * N + n) * KVRS + (part - 1) * KVD + dd] = val;
    }
}

// ---------- fused: prev outproj(+residual) halo -> conv3x3 s2 relu -> qkv ----------
template <int CPREV, int INNERP, int DPREV, int HINW, int COUT, int HOUT, int INNER, int DP,
          int KVRS, int KVD, int TPX, int BS>
__global__ void __launch_bounds__(BS) fused_oc(const float* __restrict__ o1,
                                               const float* __restrict__ ow,
                                               const float* __restrict__ ob,
                                               const float* __restrict__ zres,
                                               const float* __restrict__ cw,
                                               const float* __restrict__ cb,
                                               const float* __restrict__ qw,
                                               const float* __restrict__ qb,
                                               float* __restrict__ z, float* __restrict__ q,
                                               float* __restrict__ kv) {
    constexpr int N2 = HOUT * HOUT;
    constexpr int N1 = HINW * HINW;
    constexpr int TROWS = TPX / HOUT;     // output rows per tile
    constexpr int HR = 2 * TROWS + 1;     // halo input rows
    constexpr int HALO = HR * HINW;
    constexpr int ZSTR = COUT + 4;
    __shared__ float smem[INNERP * HALO + CPREV * HALO];
    float* o1s = smem;                    // INNERP*HALO (phase 0 only)
    float* zh  = smem + INNERP * HALO;    // CPREV*HALO
    float* zt  = smem;                    // TPX*ZSTR, overlays o1s after phase 0b
    static_assert(TPX * ZSTR <= INNERP * HALO, "zt overlay fits");
    const int b  = blockIdx.x / (N2 / TPX);
    const int n0 = (blockIdx.x % (N2 / TPX)) * TPX;
    const int tid = threadIdx.x;
    const int ho0 = n0 / HOUT;
    const int row0 = 2 * ho0 - 1;

    // phase 0a: stage o1 halo slice (coalesced)
    for (int t = tid; t < INNERP * HALO; t += BS) {
        int hd = t / HALO, p = t - hd * HALO;
        int row = row0 + p / HINW;
        float v = 0.f;
        if (row >= 0 && row < HINW)
            v = o1[((size_t)(b * INNERP + hd)) * N1 + row * HINW + (p % HINW)];
        o1s[t] = v;
    }
    __syncthreads();

    // phase 0b: outproj + bias + residual for the halo -> zh (3-way ILP over hh)
    for (int t = tid; t < CPREV * HALO; t += BS) {
        int ci = t / HALO, p = t - ci * HALO;
        int row = row0 + p / HINW;
        float val = 0.f;  // conv zero-padding
        if (row >= 0 && row < HINW) {
            int n1 = row * HINW + (p % HINW);
            const float* wp = ow + (size_t)ci * INNERP;
            float v0 = 0.f, v1 = 0.f, v2 = 0.f;
            for (int dd = 0; dd < DPREV; ++dd) {
                v0 = fmaf(wp[dd * 3 + 0], o1s[(0 * DPREV + dd) * HALO + p], v0);
                v1 = fmaf(wp[dd * 3 + 1], o1s[(1 * DPREV + dd) * HALO + p], v1);
                v2 = fmaf(wp[dd * 3 + 2], o1s[(2 * DPREV + dd) * HALO + p], v2);
            }
            val = ob[ci] + zres[((size_t)(b * CPREV) + ci) * N1 + n1] + (v0 + v1) + v2;
        }
        zh[t] = val;
    }
    __syncthreads();

    // phase 1: conv from LDS halo (+ relu); 3-way ILP over kh; zt transposed+padded
    for (int idx = tid; idx < COUT * TPX; idx += BS) {
        int c = idx / TPX, px = idx - (idx / TPX) * TPX;
        int hol = px / HOUT, wo = px - hol * HOUT;
        float a0 = cb[c], a1 = 0.f, a2 = 0.f;
        for (int ci = 0; ci < CPREV; ++ci) {
            const float* zp = zh + ci * HALO + (2 * hol) * HINW;
            const float* wp = cw + (size_t)(c * CPREV + ci) * 9;
            #pragma unroll
            for (int kw = 0; kw < 3; ++kw) {
                int col = 2 * wo + kw - 1;
                if (col < 0 || col >= HINW) continue;
                a0 = fmaf(wp[0 * 3 + kw], zp[0 * HINW + col], a0);
                a1 = fmaf(wp[1 * 3 + kw], zp[1 * HINW + col], a1);
                a2 = fmaf(wp[2 * 3 + kw], zp[2 * HINW + col], a2);
            }
        }
        float acc = fmaxf((a0 + a1) + a2, 0.f);
        zt[px * ZSTR + c] = acc;
        z[((size_t)(b * COUT) + c) * N2 + n0 + px] = acc;
    }
    __syncthreads();

    // phase 2: qkv from LDS tile (float4 LDS reads + 4 partial accumulators)
    constexpr int OC3 = 3 * INNER;
    constexpr int NF4 = COUT / 4;
    for (int idx = tid; idx < OC3 * TPX; idx += BS) {
        int oc = idx / TPX, px = idx % TPX;
        const float4* wp4 = (const float4*)(qw + (size_t)oc * COUT);
        const float4* z4  = (const float4*)(zt + px * ZSTR);
        float vs[4] = {0.f, 0.f, 0.f, 0.f};
        #pragma unroll
        for (int c4 = 0; c4 < NF4; ++c4) {
            float4 a = wp4[c4], bb = z4[c4];
            float& v = vs[c4 & 3];
            v = fmaf(a.x, bb.x, v); v = fmaf(a.y, bb.y, v);
            v = fmaf(a.z, bb.z, v); v = fmaf(a.w, bb.w, v);
        }
        float val = qb[oc] + ((vs[0] + vs[1]) + (vs[2] + vs[3]));
        int part = oc / INNER;
        int r = oc - part * INNER;
        int hh = r % 3, dd = r / 3;  // heads fastest
        size_t n = n0 + px;
        if (part == 0)
            q[((size_t)(b * 3 + hh) * N2 + n) * DP + dd] = val;
        else
            kv[((size_t)(b * 3 + hh) * N2 + n) * KVRS + (part - 1) * KVD + dd] = val;
    }
}

// ---------- attention (L1/L2): R6 config — structural floor for this decomposition ----------
// KV staged by global_load_lds DMA into wave-private LDS buffer(s); j-loop reads K/V via
// conflict-free LDS broadcasts; flat cross-wave combine. NBUF=1 when NT==1 (L2) halves LDS.
// CLOSED after R13: every in-register ILP widening (R8 prefetch pipeline, R13 2-stream
// accumulators) spilled loop-carried state to scratch (VGPR->256/128, 0.5-1GB traffic).
template <int D, int QP, int RS, int RPT, int TILE, int NW, int NBUF>
__global__ void __launch_bounds__(NW * 64) attn_big(const float* __restrict__ q,
                                                    const float* __restrict__ kv,
                                                    const float* __restrict__ table,
                                                    float* __restrict__ o, int N, int log2Hg,
                                                    int T, float scale2) {
    extern __shared__ float smem[];
    float* tb = smem;       // T floats, pre-scaled by scale2 (incl. log2e)
    float* comb = smem;     // overlays tb + kv tiles after j-loop
    constexpr int BT = NW * 64;
    constexpr int ROWS = 64 * RPT;
    constexpr int CSTR = (D % 2 == 0) ? (D + 3) : (D + 2);
    constexpr int TBYTES = TILE * RS * 4;          // bytes per tile
    constexpr int LPT = CDIV(TBYTES, 1024);        // global_load_lds calls per tile
    constexpr bool FULLT = (TBYTES % 1024) == 0;
    static_assert(LPT == 3, "vmcnt literal below assumes 3 loads per tile");

    const int bh = blockIdx.x % 96;
    const int chunk = blockIdx.x / 96;
    const int h = bh % 3;
    const int tid = threadIdx.x;
    const int wave = tid >> 6;
    const int lane = tid & 63;
    const int Hg = 1 << log2Hg;
    const int W2 = 2 * Hg - 1;
    const int base = chunk * ROWS;

    // wave-private KV tile buffer(s) (16B-aligned offset past tb)
    float* kvw = smem + ((T + 3) & ~3) + wave * (NBUF * TILE * RS);

    for (int t = tid; t < T; t += BT) tb[t] = table[t * 3 + h] * scale2;

    float qr[RPT][D];
    const float* tbp[RPT];  // per-lane bias row base: tb + ibase[r]
    #pragma unroll
    for (int r = 0; r < RPT; ++r) {
        int i = base + lane + 64 * r;
        const float* qg = q + ((size_t)bh * N + i) * QP;
        #pragma unroll
        for (int dd = 0; dd < D; ++dd) qr[r][dd] = qg[dd];
        tbp[r] = tb + (((i >> log2Hg) + Hg - 1) * W2 + (i & (Hg - 1)) + Hg - 1);
    }

    float acc[RPT][D];
    float lsum[RPT];
    #pragma unroll
    for (int r = 0; r < RPT; ++r) {
        lsum[r] = 0.f;
        #pragma unroll
        for (int dd = 0; dd < D; ++dd) acc[r][dd] = 0.f;
    }

    const float* kvbase = kv + (size_t)bh * N * RS;
    const int NJ = N / NW;
    const int NT = NJ / TILE;
    const int j0 = wave * NJ;

    // DMA one tile into LDS buffer bufIdx (wave-uniform LDS base + lane*16 linear)
    auto stage = [&](int bufIdx, int t) {
        const float* srcf = kvbase + (size_t)(j0 + t * TILE) * RS;
        float* dstf = kvw + bufIdx * (TILE * RS);
        #pragma unroll
        for (int x = 0; x < LPT; ++x) {
            if (FULLT || (x * 1024 + lane * 16) < TBYTES) {
                const void* g = (const void*)(srcf + x * 256 + lane * 4);
                void* l = (void*)(dstf + x * 256);
                __builtin_amdgcn_global_load_lds(
                    (const __attribute__((address_space(1))) void*)g,
                    (__attribute__((address_space(3))) void*)l, 16, 0, 0);
            }
        }
    };

    // prologue: stage tiles 0 and 1; the tb barrier below drains them (vmcnt(0))
    stage(0, 0);
    if (NBUF > 1 && NT > 1) stage(1, 1);

    __syncthreads();  // tb staged + prologue DMA complete

    for (int t = 0; t < NT; ++t) {
        const float* curb = kvw + (t & (NBUF - 1)) * (TILE * RS);
        const int jt = j0 + t * TILE;
        for (int jg = 0; jg < TILE; jg += 4) {
            #pragma unroll
            for (int k = 0; k < 4; ++k) {
                const int j = jt + jg + k;
                const float* kr = curb + (jg + k) * RS;  // wave-uniform LDS broadcast
                const int joff = (j >> log2Hg) * W2 + (j & (Hg - 1));
                #pragma unroll
                for (int r = 0; r < RPT; ++r) {
                    float s = 0.f;
                    #pragma unroll
                    for (int dd = 0; dd < D; ++dd) s = fmaf(qr[r][dd], kr[dd], s);
                    float e = EXP2(fmaf(s, scale2, tbp[r][-joff]));
                    lsum[r] += e;
                    #pragma unroll
                    for (int dd = 0; dd < D; ++dd) acc[r][dd] = fmaf(e, kr[D + dd], acc[r][dd]);
                }
            }
        }
        if (NBUF > 1 && t + 2 < NT) {
            // all reads of buf[t&1] done (DS in-order) before DMA may overwrite it
            asm volatile("s_waitcnt lgkmcnt(0)" ::: "memory");
            stage(t & 1, t + 2);
            waitcnt_vm<3>();   // tile t+1 resident; tile t+2's 3 loads stay in flight
        } else if (NBUF > 1 && t + 1 < NT) {
            waitcnt_vm<0>();   // last tile: drain
        }
    }

    __syncthreads();
    #pragma unroll
    for (int r = 0; r < RPT; ++r) {
        float* cp = comb + (size_t)(wave * ROWS + lane + 64 * r) * CSTR;
        #pragma unroll
        for (int dd = 0; dd < D; ++dd) cp[dd] = acc[r][dd];
        cp[D] = lsum[r];
    }
    __syncthreads();
    if (tid < ROWS) {
        float af[D];
        #pragma unroll
        for (int dd = 0; dd < D; ++dd) af[dd] = 0.f;
        float lf = 0.f;
        #pragma unroll
        for (int wv = 0; wv < NW; ++wv) {
            const float* cp = comb + (size_t)(wv * ROWS + tid) * CSTR;
            #pragma unroll
            for (int dd = 0; dd < D; ++dd) af[dd] += cp[dd];
            lf += cp[D];
        }
        float inv = 1.0f / lf;
        int i = base + tid;
        #pragma unroll
        for (int dd = 0; dd < D; ++dd)
            o[((size_t)bh * D + dd) * N + i] = af[dd] * inv;  // O layout [bh][d][N]
    }
}

// ---------- L3 attention: one block per bh; KV+table staged in LDS; 8-wave j-split ----------
__global__ void __launch_bounds__(512) attn_small(const float* __restrict__ q,
                                                  const float* __restrict__ kv,
                                                  const float* __restrict__ table,
                                                  float* __restrict__ o, float scale2) {
    constexpr int D = 21, DP = 24, NN = 64;
    constexpr int CSTR = 23;
    __shared__ float smem[8 * NN * CSTR];  // 47104 B; comb overlays kvs/tb
    float* kvs = smem;
    float* tb = kvs + NN * 2 * DP;
    float* comb = smem;

    const int bh = blockIdx.x;     // 96 blocks
    const int h = bh % 3;
    const int tid = threadIdx.x;
    const int wave = tid >> 6;
    const int lane = tid & 63;

    {
        const float4* kvg = (const float4*)(kv + (size_t)bh * NN * 2 * DP);
        float4* kvs4 = (float4*)kvs;
        for (int t = tid; t < NN * 2 * DP / 4; t += 512) kvs4[t] = kvg[t];
        for (int t = tid; t < 225; t += 512) tb[t] = table[t * 3 + h] * scale2;
    }

    const int i = lane;
    const float* qg = q + ((size_t)bh * NN + i) * DP;
    float qr[D];
    #pragma unroll
    for (int dd = 0; dd < D; ++dd) qr[dd] = qg[dd];
    const int ibase = ((i >> 3) + 7) * 15 + (i & 7) + 7;
    __syncthreads();

    float acc[D];
    #pragma unroll
    for (int dd = 0; dd < D; ++dd) acc[dd] = 0.f;
    float lsum = 0.f;

    const int j0 = wave * 8;   // 8 waves x 8 js
    #pragma unroll
    for (int jj = 0; jj < 8; ++jj) {
        const int j = j0 + jj;
        float4 r4[12];
        const float4* rp = (const float4*)(kvs + j * 2 * DP);
        #pragma unroll
        for (int x = 0; x < 12; ++x) r4[x] = rp[x];
        const float* kr = (const float*)r4;
        const float* vr = kr + DP;
        const int joff = (j >> 3) * 15 + (j & 7);
        float s = 0.f;
        #pragma unroll
        for (int dd = 0; dd < D; ++dd) s = fmaf(qr[dd], kr[dd], s);
        float e = EXP2(fmaf(s, scale2, tb[ibase - joff]));
        lsum += e;
        #pragma unroll
        for (int dd = 0; dd < D; ++dd) acc[dd] = fmaf(e, vr[dd], acc[dd]);
    }

    __syncthreads();
    {
        float* cp = comb + (size_t)(wave * NN + lane) * CSTR;
        #pragma unroll
        for (int dd = 0; dd < D; ++dd) cp[dd] = acc[dd];
        cp[D] = lsum;
    }
    __syncthreads();
    if (tid < NN) {
        float af[D];
        #pragma unroll
        for (int dd = 0; dd < D; ++dd) af[dd] = 0.f;
        float lf = 0.f;
        #pragma unroll
        for (int wv = 0; wv < 8; ++wv) {
            const float* cp = comb + (size_t)(wv * NN + tid) * CSTR;
            #pragma unroll
            for (int dd = 0; dd < D; ++dd) af[dd] += cp[dd];
            lf += cp[D];
        }
        float inv = 1.0f / lf;
        #pragma unroll
        for (int dd = 0; dd < D; ++dd)
            o[((size_t)bh * D + dd) * NN + tid] = af[dd] * inv;
    }
}

// ---------- tail: outproj3 + global-avg-pool + classifier (3-way ILP over hh) ----------
__global__ void __launch_bounds__(256) tail(const float* __restrict__ o,
                                            const float* __restrict__ ow,
                                            const float* __restrict__ ob,
                                            const float* __restrict__ zin,
                                            const float* __restrict__ cw,
                                            const float* __restrict__ cb,
                                            float* __restrict__ out) {
    __shared__ float os[63 * 64];
    __shared__ float zt[64 * 65];
    __shared__ float p[64];
    const int b = blockIdx.x;
    const int tid = threadIdx.x;
    // stage o[b]: rows b*63..b*63+62 are contiguous (layout [bh][d][N], hd = hh*21+dd)
    for (int t = tid; t < 63 * 64; t += 256) os[t] = o[(size_t)(b * 63) * 64 + t];
    __syncthreads();
    for (int idx = tid; idx < 64 * 64; idx += 256) {
        int c = idx >> 6, n = idx & 63;
        const float* wp = ow + (size_t)c * 63;
        float v0 = 0.f, v1 = 0.f, v2 = 0.f;
        for (int dd = 0; dd < 21; ++dd) {
            v0 = fmaf(wp[dd * 3 + 0], os[(0  + dd) * 64 + n], v0);
            v1 = fmaf(wp[dd * 3 + 1], os[(21 + dd) * 64 + n], v1);
            v2 = fmaf(wp[dd * 3 + 2], os[(42 + dd) * 64 + n], v2);
        }
        zt[c * 65 + n] = ob[c] + zin[((size_t)(b * 64) + c) * 64 + n] + (v0 + v1) + v2;
    }
    __syncthreads();
    if (tid < 64) {
        float s = 0.f;
        #pragma unroll
        for (int n = 0; n < 64; ++n) s += zt[tid * 65 + n];
        s *= (1.0f / 64.0f);
        p[tid] = s;
        out[b * 64 + tid] = s;
    }
    __syncthreads();
    if (tid < 10) {
        float val = cb[tid];
        const float* wp = cw + (size_t)tid * 64;
        #pragma unroll
        for (int kk = 0; kk < 64; ++kk) val = fmaf(wp[kk], p[kk], val);
        out[2048 + b * 10 + tid] = val;
    }
}

extern "C" void kernel_launch(void* const* d_in, const int* in_sizes, int n_in,
                              void* d_out, int out_size, void* d_ws, size_t ws_size,
                              hipStream_t stream) {
    float* ws = (float*)d_ws;
    float* Zc1 = ws;                 // conv1 z (524288) / later conv3 z (131072)
    float* Zc2 = Zc1 + 524288;       // conv2 z (262144)
    float* Q   = Zc2 + 262144;       // 786432 (96*1024*8 max)
    float* KV  = Q + 786432;         // 1572864 region (L1 packed uses 96*1024*12)
    float* O   = KV + 1572864;       // 491520 (96*1024*5 max)

    float* out = (float*)d_out;

    // ===== layer 1: Cin=1 H64->32, dim=16, inner=15, d=5 (q pad 8, kv stride 12), N=1024 =====
    conv_qkv<1, 64, 16, 32, 15, 8, 12, 5, 32, 512><<<32 * 32, 512, 0, stream>>>(
        (const float*)d_in[0], (const float*)d_in[1], (const float*)d_in[2],
        (const float*)d_in[3], (const float*)d_in[4], Zc1, Q, KV);
    // R6-exact: RPT=2, NW=4, TILE=64, NBUF=2, 768 blocks; smem = (3972 + 4*2*64*12)*4 = 40464 B
    attn_big<5, 8, 12, 2, 64, 4, 2><<<96 * 8, 256, 40464, stream>>>(
        Q, KV, (const float*)d_in[7], O, 1024, 5, 3969, SC5);

    // ===== layer 2 (fused outproj1 + conv2 + qkv2): dim=32, d=10 (q pad 12, kv stride 20), N=256 =====
    fused_oc<16, 15, 5, 32, 32, 16, 30, 12, 20, 10, 16, 512><<<32 * 16, 512, 0, stream>>>(
        O, (const float*)d_in[5], (const float*)d_in[6], Zc1,
        (const float*)d_in[8], (const float*)d_in[9],
        (const float*)d_in[10], (const float*)d_in[11], Zc2, Q, KV);
    // NW=8, RPT=1, TILE=32, NBUF=1 (NT=1); smem = max(964+8*32*20, comb 8*64*13)*4 = 26624 B
    attn_big<10, 12, 20, 1, 32, 8, 1><<<96 * 4, 512, 26624, stream>>>(
        Q, KV, (const float*)d_in[14], O, 256, 4, 961, SC10);

    // ===== layer 3 (fused outproj2 + conv3 + qkv3): dim=64, d=21 (DP=24, kv interleaved 48) =====
    fused_oc<32, 30, 10, 16, 64, 8, 63, 24, 48, 24, 8, 512><<<32 * 8, 512, 0, stream>>>(
        O, (const float*)d_in[12], (const float*)d_in[13], Zc2,
        (const float*)d_in[15], (const float*)d_in[16],
        (const float*)d_in[17], (const float*)d_in[18], Zc1, Q, KV);
    attn_small<<<96, 512, 0, stream>>>(Q, KV, (const float*)d_in[21], O, SC21);

    // ===== head =====
    tail<<<32, 256, 0, stream>>>(
        O, (const float*)d_in[19], (const float*)d_in[20], Zc1,
        (const float*)d_in[22], (const float*)d_in[23], out);
}

// Round 15
// 245.171 us; speedup vs baseline: 1.9730x; 1.0168x over previous
//
#include <hip/hip_runtime.h>
#include <math.h>

#define CDIV(a, b) (((a) + (b) - 1) / (b))

#define LOG2E 1.4426950408889634f
#define SC5  (0.44721359549996f * LOG2E)
#define SC10 (0.31622776601684f * LOG2E)
#define SC21 (0.21821789023599f * LOG2E)
#define EXP2(x) __builtin_amdgcn_exp2f(x)

template <int N> __device__ inline void waitcnt_vm() {
    if constexpr (N == 0) asm volatile("s_waitcnt vmcnt(0)" ::: "memory");
    else if constexpr (N == 3) asm volatile("s_waitcnt vmcnt(3)" ::: "memory");
    else static_assert(N < 0, "unsupported vmcnt literal");
}

// ---------- fused 3x3 s2 conv + relu + qkv projection (layer 1 only) ----------
// zt stored TRANSPOSED+padded [px][COUT+4] so phase-2 reads are float4 LDS loads.
template <int CIN, int HIN, int COUT, int HOUT, int INNER, int DP, int KVRS, int KVD, int TPX,
          int BS>
__global__ void __launch_bounds__(BS) conv_qkv(const float* __restrict__ in,
                                               const float* __restrict__ cw,
                                               const float* __restrict__ cb,
                                               const float* __restrict__ qw,
                                               const float* __restrict__ qb,
                                               float* __restrict__ z, float* __restrict__ q,
                                               float* __restrict__ kv) {
    constexpr int N = HOUT * HOUT;
    constexpr int ZSTR = COUT + 4;          // pad: bank spread + keeps 16B alignment
    __shared__ float zt[TPX * ZSTR];
    const int b  = blockIdx.x / (N / TPX);
    const int n0 = (blockIdx.x % (N / TPX)) * TPX;
    const int tid = threadIdx.x;

    for (int idx = tid; idx < COUT * TPX; idx += BS) {
        int c = idx / TPX, px = idx % TPX;
        int n = n0 + px;
        int ho = n / HOUT, wo = n % HOUT;
        float a0 = cb[c], a1 = 0.f, a2 = 0.f;     // 3-way ILP over kh
        for (int ci = 0; ci < CIN; ++ci) {
            const float* ip = in + (size_t)(b * CIN + ci) * HIN * HIN;
            const float* wp = cw + (size_t)(c * CIN + ci) * 9;
            #pragma unroll
            for (int kh = 0; kh < 3; ++kh) {
                int hi = 2 * ho + kh - 1;
                if (hi < 0 || hi >= HIN) continue;
                float av = 0.f;
                #pragma unroll
                for (int kw = 0; kw < 3; ++kw) {
                    int wi = 2 * wo + kw - 1;
                    if (wi < 0 || wi >= HIN) continue;
                    av = fmaf(wp[kh * 3 + kw], ip[hi * HIN + wi], av);
                }
                if (kh == 0) a0 += av; else if (kh == 1) a1 += av; else a2 += av;
            }
        }
        float acc = fmaxf((a0 + a1) + a2, 0.f);
        zt[px * ZSTR + c] = acc;
        z[((size_t)(b * COUT) + c) * N + n] = acc;
    }
    __syncthreads();

    constexpr int OC3 = 3 * INNER;
    constexpr int NF4 = COUT / 4;
    for (int idx = tid; idx < OC3 * TPX; idx += BS) {
        int oc = idx / TPX, px = idx % TPX;
        const float4* wp4 = (const float4*)(qw + (size_t)oc * COUT);
        const float4* z4  = (const float4*)(zt + px * ZSTR);
        float vs[4] = {0.f, 0.f, 0.f, 0.f};
        #pragma unroll
        for (int c4 = 0; c4 < NF4; ++c4) {
            float4 a = wp4[c4], bb = z4[c4];
            float& v = vs[c4 & 3];
            v = fmaf(a.x, bb.x, v); v = fmaf(a.y, bb.y, v);
            v = fmaf(a.z, bb.z, v); v = fmaf(a.w, bb.w, v);
        }
        float val = qb[oc] + ((vs[0] + vs[1]) + (vs[2] + vs[3]));
        int part = oc / INNER;
        int r = oc - part * INNER;
        int hh = r % 3, dd = r / 3;  // heads fastest
        size_t n = n0 + px;
        if (part == 0)
            q[((size_t)(b * 3 + hh) * N + n) * DP + dd] = val;
        else
            kv[((size_t)(b * 3 + hh) * N + n) * KVRS + (part - 1) * KVD + dd] = val;
    }
}

// ---------- fused: prev outproj(+residual) halo -> conv3x3 s2 relu -> qkv ----------
template <int CPREV, int INNERP, int DPREV, int HINW, int COUT, int HOUT, int INNER, int DP,
          int KVRS, int KVD, int TPX, int BS>
__global__ void __launch_bounds__(BS) fused_oc(const float* __restrict__ o1,
                                               const float* __restrict__ ow,
                                               const float* __restrict__ ob,
                                               const float* __restrict__ zres,
                                               const float* __restrict__ cw,
                                               const float* __restrict__ cb,
                                               const float* __restrict__ qw,
                                               const float* __restrict__ qb,
                                               float* __restrict__ z, float* __restrict__ q,
                                               float* __restrict__ kv) {
    constexpr int N2 = HOUT * HOUT;
    constexpr int N1 = HINW * HINW;
    constexpr int TROWS = TPX / HOUT;     // output rows per tile
    constexpr int HR = 2 * TROWS + 1;     // halo input rows
    constexpr int HALO = HR * HINW;
    constexpr int ZSTR = COUT + 4;
    __shared__ float smem[INNERP * HALO + CPREV * HALO];
    float* o1s = smem;                    // INNERP*HALO (phase 0 only)
    float* zh  = smem + INNERP * HALO;    // CPREV*HALO
    float* zt  = smem;                    // TPX*ZSTR, overlays o1s after phase 0b
    static_assert(TPX * ZSTR <= INNERP * HALO, "zt overlay fits");
    const int b  = blockIdx.x / (N2 / TPX);
    const int n0 = (blockIdx.x % (N2 / TPX)) * TPX;
    const int tid = threadIdx.x;
    const int ho0 = n0 / HOUT;
    const int row0 = 2 * ho0 - 1;

    // phase 0a: stage o1 halo slice (coalesced)
    for (int t = tid; t < INNERP * HALO; t += BS) {
        int hd = t / HALO, p = t - hd * HALO;
        int row = row0 + p / HINW;
        float v = 0.f;
        if (row >= 0 && row < HINW)
            v = o1[((size_t)(b * INNERP + hd)) * N1 + row * HINW + (p % HINW)];
        o1s[t] = v;
    }
    __syncthreads();

    // phase 0b: outproj + bias + residual for the halo -> zh (3-way ILP over hh)
    for (int t = tid; t < CPREV * HALO; t += BS) {
        int ci = t / HALO, p = t - ci * HALO;
        int row = row0 + p / HINW;
        float val = 0.f;  // conv zero-padding
        if (row >= 0 && row < HINW) {
            int n1 = row * HINW + (p % HINW);
            const float* wp = ow + (size_t)ci * INNERP;
            float v0 = 0.f, v1 = 0.f, v2 = 0.f;
            for (int dd = 0; dd < DPREV; ++dd) {
                v0 = fmaf(wp[dd * 3 + 0], o1s[(0 * DPREV + dd) * HALO + p], v0);
                v1 = fmaf(wp[dd * 3 + 1], o1s[(1 * DPREV + dd) * HALO + p], v1);
                v2 = fmaf(wp[dd * 3 + 2], o1s[(2 * DPREV + dd) * HALO + p], v2);
            }
            val = ob[ci] + zres[((size_t)(b * CPREV) + ci) * N1 + n1] + (v0 + v1) + v2;
        }
        zh[t] = val;
    }
    __syncthreads();

    // phase 1: conv from LDS halo (+ relu); 3-way ILP over kh; zt transposed+padded
    for (int idx = tid; idx < COUT * TPX; idx += BS) {
        int c = idx / TPX, px = idx - (idx / TPX) * TPX;
        int hol = px / HOUT, wo = px - hol * HOUT;
        float a0 = cb[c], a1 = 0.f, a2 = 0.f;
        for (int ci = 0; ci < CPREV; ++ci) {
            const float* zp = zh + ci * HALO + (2 * hol) * HINW;
            const float* wp = cw + (size_t)(c * CPREV + ci) * 9;
            #pragma unroll
            for (int kw = 0; kw < 3; ++kw) {
                int col = 2 * wo + kw - 1;
                if (col < 0 || col >= HINW) continue;
                a0 = fmaf(wp[0 * 3 + kw], zp[0 * HINW + col], a0);
                a1 = fmaf(wp[1 * 3 + kw], zp[1 * HINW + col], a1);
                a2 = fmaf(wp[2 * 3 + kw], zp[2 * HINW + col], a2);
            }
        }
        float acc = fmaxf((a0 + a1) + a2, 0.f);
        zt[px * ZSTR + c] = acc;
        z[((size_t)(b * COUT) + c) * N2 + n0 + px] = acc;
    }
    __syncthreads();

    // phase 2: qkv from LDS tile (float4 LDS reads + 4 partial accumulators)
    constexpr int OC3 = 3 * INNER;
    constexpr int NF4 = COUT / 4;
    for (int idx = tid; idx < OC3 * TPX; idx += BS) {
        int oc = idx / TPX, px = idx % TPX;
        const float4* wp4 = (const float4*)(qw + (size_t)oc * COUT);
        const float4* z4  = (const float4*)(zt + px * ZSTR);
        float vs[4] = {0.f, 0.f, 0.f, 0.f};
        #pragma unroll
        for (int c4 = 0; c4 < NF4; ++c4) {
            float4 a = wp4[c4], bb = z4[c4];
            float& v = vs[c4 & 3];
            v = fmaf(a.x, bb.x, v); v = fmaf(a.y, bb.y, v);
            v = fmaf(a.z, bb.z, v); v = fmaf(a.w, bb.w, v);
        }
        float val = qb[oc] + ((vs[0] + vs[1]) + (vs[2] + vs[3]));
        int part = oc / INNER;
        int r = oc - part * INNER;
        int hh = r % 3, dd = r / 3;  // heads fastest
        size_t n = n0 + px;
        if (part == 0)
            q[((size_t)(b * 3 + hh) * N2 + n) * DP + dd] = val;
        else
            kv[((size_t)(b * 3 + hh) * N2 + n) * KVRS + (part - 1) * KVD + dd] = val;
    }
}

// ---------- attention (L1/L2): R6 config + SALU-offloaded uniform address math ----------
// KV staged by global_load_lds DMA into wave-private LDS buffer(s); j-loop reads K/V via
// conflict-free LDS broadcasts; flat cross-wave combine. `wave` is readfirstlane-pinned:
// all j/joff/buffer arithmetic is provably wave-uniform -> SALU (R3 evidence: busy-work
// -24%). R3's s_load hazard is structurally gone — KV is consumed from LDS (no scalar LDS
// path) and DMA staging uses per-lane global addresses.
template <int D, int QP, int RS, int RPT, int TILE, int NW, int NBUF>
__global__ void __launch_bounds__(NW * 64) attn_big(const float* __restrict__ q,
                                                    const float* __restrict__ kv,
                                                    const float* __restrict__ table,
                                                    float* __restrict__ o, int N, int log2Hg,
                                                    int T, float scale2) {
    extern __shared__ float smem[];
    float* tb = smem;       // T floats, pre-scaled by scale2 (incl. log2e)
    float* comb = smem;     // overlays tb + kv tiles after j-loop
    constexpr int BT = NW * 64;
    constexpr int ROWS = 64 * RPT;
    constexpr int CSTR = (D % 2 == 0) ? (D + 3) : (D + 2);
    constexpr int TBYTES = TILE * RS * 4;          // bytes per tile
    constexpr int LPT = CDIV(TBYTES, 1024);        // global_load_lds calls per tile
    constexpr bool FULLT = (TBYTES % 1024) == 0;
    static_assert(LPT == 3, "vmcnt literal below assumes 3 loads per tile");

    const int bh = blockIdx.x % 96;
    const int chunk = blockIdx.x / 96;
    const int h = bh % 3;
    const int tid = threadIdx.x;
    const int wave = __builtin_amdgcn_readfirstlane(tid >> 6);  // wave-uniform -> SGPR
    const int lane = tid & 63;
    const int Hg = 1 << log2Hg;
    const int W2 = 2 * Hg - 1;
    const int base = chunk * ROWS;

    // wave-private KV tile buffer(s) (16B-aligned offset past tb)
    float* kvw = smem + ((T + 3) & ~3) + wave * (NBUF * TILE * RS);

    for (int t = tid; t < T; t += BT) tb[t] = table[t * 3 + h] * scale2;

    float qr[RPT][D];
    const float* tbp[RPT];  // per-lane bias row base: tb + ibase[r]
    #pragma unroll
    for (int r = 0; r < RPT; ++r) {
        int i = base + lane + 64 * r;
        const float* qg = q + ((size_t)bh * N + i) * QP;
        #pragma unroll
        for (int dd = 0; dd < D; ++dd) qr[r][dd] = qg[dd];
        tbp[r] = tb + (((i >> log2Hg) + Hg - 1) * W2 + (i & (Hg - 1)) + Hg - 1);
    }

    float acc[RPT][D];
    float lsum[RPT];
    #pragma unroll
    for (int r = 0; r < RPT; ++r) {
        lsum[r] = 0.f;
        #pragma unroll
        for (int dd = 0; dd < D; ++dd) acc[r][dd] = 0.f;
    }

    const float* kvbase = kv + (size_t)bh * N * RS;
    const int NJ = N / NW;
    const int NT = NJ / TILE;
    const int j0 = wave * NJ;

    // DMA one tile into LDS buffer bufIdx (wave-uniform LDS base + lane*16 linear)
    auto stage = [&](int bufIdx, int t) {
        const float* srcf = kvbase + (size_t)(j0 + t * TILE) * RS;
        float* dstf = kvw + bufIdx * (TILE * RS);
        #pragma unroll
        for (int x = 0; x < LPT; ++x) {
            if (FULLT || (x * 1024 + lane * 16) < TBYTES) {
                const void* g = (const void*)(srcf + x * 256 + lane * 4);
                void* l = (void*)(dstf + x * 256);
                __builtin_amdgcn_global_load_lds(
                    (const __attribute__((address_space(1))) void*)g,
                    (__attribute__((address_space(3))) void*)l, 16, 0, 0);
            }
        }
    };

    // prologue: stage tiles 0 and 1; the tb barrier below drains them (vmcnt(0))
    stage(0, 0);
    if (NBUF > 1 && NT > 1) stage(1, 1);

    __syncthreads();  // tb staged + prologue DMA complete

    for (int t = 0; t < NT; ++t) {
        const float* curb = kvw + (t & (NBUF - 1)) * (TILE * RS);
        const int jt = j0 + t * TILE;
        for (int jg = 0; jg < TILE; jg += 4) {
            #pragma unroll
            for (int k = 0; k < 4; ++k) {
                const int j = jt + jg + k;
                const float* kr = curb + (jg + k) * RS;  // wave-uniform LDS broadcast
                const int joff = (j >> log2Hg) * W2 + (j & (Hg - 1));
                #pragma unroll
                for (int r = 0; r < RPT; ++r) {
                    float s = 0.f;
                    #pragma unroll
                    for (int dd = 0; dd < D; ++dd) s = fmaf(qr[r][dd], kr[dd], s);
                    float e = EXP2(fmaf(s, scale2, tbp[r][-joff]));
                    lsum[r] += e;
                    #pragma unroll
                    for (int dd = 0; dd < D; ++dd) acc[r][dd] = fmaf(e, kr[D + dd], acc[r][dd]);
                }
            }
        }
        if (NBUF > 1 && t + 2 < NT) {
            // all reads of buf[t&1] done (DS in-order) before DMA may overwrite it
            asm volatile("s_waitcnt lgkmcnt(0)" ::: "memory");
            stage(t & 1, t + 2);
            waitcnt_vm<3>();   // tile t+1 resident; tile t+2's 3 loads stay in flight
        } else if (NBUF > 1 && t + 1 < NT) {
            waitcnt_vm<0>();   // last tile: drain
        }
    }

    __syncthreads();
    #pragma unroll
    for (int r = 0; r < RPT; ++r) {
        float* cp = comb + (size_t)(wave * ROWS + lane + 64 * r) * CSTR;
        #pragma unroll
        for (int dd = 0; dd < D; ++dd) cp[dd] = acc[r][dd];
        cp[D] = lsum[r];
    }
    __syncthreads();
    if (tid < ROWS) {
        float af[D];
        #pragma unroll
        for (int dd = 0; dd < D; ++dd) af[dd] = 0.f;
        float lf = 0.f;
        #pragma unroll
        for (int wv = 0; wv < NW; ++wv) {
            const float* cp = comb + (size_t)(wv * ROWS + tid) * CSTR;
            #pragma unroll
            for (int dd = 0; dd < D; ++dd) af[dd] += cp[dd];
            lf += cp[D];
        }
        float inv = 1.0f / lf;
        int i = base + tid;
        #pragma unroll
        for (int dd = 0; dd < D; ++dd)
            o[((size_t)bh * D + dd) * N + i] = af[dd] * inv;  // O layout [bh][d][N]
    }
}

// ---------- L3 attention: one block per bh; KV+table staged in LDS; 8-wave j-split ----------
__global__ void __launch_bounds__(512) attn_small(const float* __restrict__ q,
                                                  const float* __restrict__ kv,
                                                  const float* __restrict__ table,
                                                  float* __restrict__ o, float scale2) {
    constexpr int D = 21, DP = 24, NN = 64;
    constexpr int CSTR = 23;
    __shared__ float smem[8 * NN * CSTR];  // 47104 B; comb overlays kvs/tb
    float* kvs = smem;
    float* tb = kvs + NN * 2 * DP;
    float* comb = smem;

    const int bh = blockIdx.x;     // 96 blocks
    const int h = bh % 3;
    const int tid = threadIdx.x;
    const int wave = tid >> 6;
    const int lane = tid & 63;

    {
        const float4* kvg = (const float4*)(kv + (size_t)bh * NN * 2 * DP);
        float4* kvs4 = (float4*)kvs;
        for (int t = tid; t < NN * 2 * DP / 4; t += 512) kvs4[t] = kvg[t];
        for (int t = tid; t < 225; t += 512) tb[t] = table[t * 3 + h] * scale2;
    }

    const int i = lane;
    const float* qg = q + ((size_t)bh * NN + i) * DP;
    float qr[D];
    #pragma unroll
    for (int dd = 0; dd < D; ++dd) qr[dd] = qg[dd];
    const int ibase = ((i >> 3) + 7) * 15 + (i & 7) + 7;
    __syncthreads();

    float acc[D];
    #pragma unroll
    for (int dd = 0; dd < D; ++dd) acc[dd] = 0.f;
    float lsum = 0.f;

    const int j0 = wave * 8;   // 8 waves x 8 js
    #pragma unroll
    for (int jj = 0; jj < 8; ++jj) {
        const int j = j0 + jj;
        float4 r4[12];
        const float4* rp = (const float4*)(kvs + j * 2 * DP);
        #pragma unroll
        for (int x = 0; x < 12; ++x) r4[x] = rp[x];
        const float* kr = (const float*)r4;
        const float* vr = kr + DP;
        const int joff = (j >> 3) * 15 + (j & 7);
        float s = 0.f;
        #pragma unroll
        for (int dd = 0; dd < D; ++dd) s = fmaf(qr[dd], kr[dd], s);
        float e = EXP2(fmaf(s, scale2, tb[ibase - joff]));
        lsum += e;
        #pragma unroll
        for (int dd = 0; dd < D; ++dd) acc[dd] = fmaf(e, vr[dd], acc[dd]);
    }

    __syncthreads();
    {
        float* cp = comb + (size_t)(wave * NN + lane) * CSTR;
        #pragma unroll
        for (int dd = 0; dd < D; ++dd) cp[dd] = acc[dd];
        cp[D] = lsum;
    }
    __syncthreads();
    if (tid < NN) {
        float af[D];
        #pragma unroll
        for (int dd = 0; dd < D; ++dd) af[dd] = 0.f;
        float lf = 0.f;
        #pragma unroll
        for (int wv = 0; wv < 8; ++wv) {
            const float* cp = comb + (size_t)(wv * NN + tid) * CSTR;
            #pragma unroll
            for (int dd = 0; dd < D; ++dd) af[dd] += cp[dd];
            lf += cp[D];
        }
        float inv = 1.0f / lf;
        #pragma unroll
        for (int dd = 0; dd < D; ++dd)
            o[((size_t)bh * D + dd) * NN + tid] = af[dd] * inv;
    }
}

// ---------- tail: outproj3 + global-avg-pool + classifier (3-way ILP over hh) ----------
__global__ void __launch_bounds__(256) tail(const float* __restrict__ o,
                                            const float* __restrict__ ow,
                                            const float* __restrict__ ob,
                                            const float* __restrict__ zin,
                                            const float* __restrict__ cw,
                                            const float* __restrict__ cb,
                                            float* __restrict__ out) {
    __shared__ float os[63 * 64];
    __shared__ float zt[64 * 65];
    __shared__ float p[64];
    const int b = blockIdx.x;
    const int tid = threadIdx.x;
    // stage o[b]: rows b*63..b*63+62 are contiguous (layout [bh][d][N], hd = hh*21+dd)
    for (int t = tid; t < 63 * 64; t += 256) os[t] = o[(size_t)(b * 63) * 64 + t];
    __syncthreads();
    for (int idx = tid; idx < 64 * 64; idx += 256) {
        int c = idx >> 6, n = idx & 63;
        const float* wp = ow + (size_t)c * 63;
        float v0 = 0.f, v1 = 0.f, v2 = 0.f;
        for (int dd = 0; dd < 21; ++dd) {
            v0 = fmaf(wp[dd * 3 + 0], os[(0  + dd) * 64 + n], v0);
            v1 = fmaf(wp[dd * 3 + 1], os[(21 + dd) * 64 + n], v1);
            v2 = fmaf(wp[dd * 3 + 2], os[(42 + dd) * 64 + n], v2);
        }
        zt[c * 65 + n] = ob[c] + zin[((size_t)(b * 64) + c) * 64 + n] + (v0 + v1) + v2;
    }
    __syncthreads();
    if (tid < 64) {
        float s = 0.f;
        #pragma unroll
        for (int n = 0; n < 64; ++n) s += zt[tid * 65 + n];
        s *= (1.0f / 64.0f);
        p[tid] = s;
        out[b * 64 + tid] = s;
    }
    __syncthreads();
    if (tid < 10) {
        float val = cb[tid];
        const float* wp = cw + (size_t)tid * 64;
        #pragma unroll
        for (int kk = 0; kk < 64; ++kk) val = fmaf(wp[kk], p[kk], val);
        out[2048 + b * 10 + tid] = val;
    }
}

extern "C" void kernel_launch(void* const* d_in, const int* in_sizes, int n_in,
                              void* d_out, int out_size, void* d_ws, size_t ws_size,
                              hipStream_t stream) {
    float* ws = (float*)d_ws;
    float* Zc1 = ws;                 // conv1 z (524288) / later conv3 z (131072)
    float* Zc2 = Zc1 + 524288;       // conv2 z (262144)
    float* Q   = Zc2 + 262144;       // 786432 (96*1024*8 max)
    float* KV  = Q + 786432;         // 1572864 region (L1 packed uses 96*1024*12)
    float* O   = KV + 1572864;       // 491520 (96*1024*5 max)

    float* out = (float*)d_out;

    // ===== layer 1: Cin=1 H64->32, dim=16, inner=15, d=5 (q pad 8, kv stride 12), N=1024 =====
    conv_qkv<1, 64, 16, 32, 15, 8, 12, 5, 32, 512><<<32 * 32, 512, 0, stream>>>(
        (const float*)d_in[0], (const float*)d_in[1], (const float*)d_in[2],
        (const float*)d_in[3], (const float*)d_in[4], Zc1, Q, KV);
    // R6-exact shape + SALU wave pin: RPT=2, NW=4, TILE=64, NBUF=2, 768 blocks
    attn_big<5, 8, 12, 2, 64, 4, 2><<<96 * 8, 256, 40464, stream>>>(
        Q, KV, (const float*)d_in[7], O, 1024, 5, 3969, SC5);

    // ===== layer 2 (fused outproj1 + conv2 + qkv2): dim=32, d=10 (q pad 12, kv stride 20), N=256 =====
    fused_oc<16, 15, 5, 32, 32, 16, 30, 12, 20, 10, 16, 512><<<32 * 16, 512, 0, stream>>>(
        O, (const float*)d_in[5], (const float*)d_in[6], Zc1,
        (const float*)d_in[8], (const float*)d_in[9],
        (const float*)d_in[10], (const float*)d_in[11], Zc2, Q, KV);
    // NW=8, RPT=1, TILE=32, NBUF=1 (NT=1); smem = max(964+8*32*20, comb 8*64*13)*4 = 26624 B
    attn_big<10, 12, 20, 1, 32, 8, 1><<<96 * 4, 512, 26624, stream>>>(
        Q, KV, (const float*)d_in[14], O, 256, 4, 961, SC10);

    // ===== layer 3 (fused outproj2 + conv3 + qkv3): dim=64, d=21 (DP=24, kv interleaved 48) =====
    fused_oc<32, 30, 10, 16, 64, 8, 63, 24, 48, 24, 8, 512><<<32 * 8, 512, 0, stream>>>(
        O, (const float*)d_in[12], (const float*)d_in[13], Zc2,
        (const float*)d_in[15], (const float*)d_in[16],
        (const float*)d_in[17], (const float*)d_in[18], Zc1, Q, KV);
    attn_small<<<96, 512, 0, stream>>>(Q, KV, (const float*)d_in[21], O, SC21);

    // ===== head =====
    tail<<<32, 256, 0, stream>>>(
        O, (const float*)d_in[19], (const float*)d_in[20], Zc1,
        (const float*)d_in[22], (const float*)d_in[23], out);
}

// Round 16
// 243.898 us; speedup vs baseline: 1.9833x; 1.0052x over previous
//
#include <hip/hip_runtime.h>
#include <math.h>

#define CDIV(a, b) (((a) + (b) - 1) / (b))

#define LOG2E 1.4426950408889634f
#define SC5  (0.44721359549996f * LOG2E)
#define SC10 (0.31622776601684f * LOG2E)
#define SC21 (0.21821789023599f * LOG2E)
#define EXP2(x) __builtin_amdgcn_exp2f(x)

template <int N> __device__ inline void waitcnt_vm() {
    if constexpr (N == 0) asm volatile("s_waitcnt vmcnt(0)" ::: "memory");
    else if constexpr (N == 3) asm volatile("s_waitcnt vmcnt(3)" ::: "memory");
    else static_assert(N < 0, "unsupported vmcnt literal");
}

// ---------- fused 3x3 s2 conv + relu + qkv projection (layer 1 only) ----------
// zt stored TRANSPOSED+padded [px][COUT+4] so phase-2 reads are float4 LDS loads.
template <int CIN, int HIN, int COUT, int HOUT, int INNER, int DP, int KVRS, int KVD, int TPX,
          int BS>
__global__ void __launch_bounds__(BS) conv_qkv(const float* __restrict__ in,
                                               const float* __restrict__ cw,
                                               const float* __restrict__ cb,
                                               const float* __restrict__ qw,
                                               const float* __restrict__ qb,
                                               float* __restrict__ z, float* __restrict__ q,
                                               float* __restrict__ kv) {
    constexpr int N = HOUT * HOUT;
    constexpr int ZSTR = COUT + 4;          // pad: bank spread + keeps 16B alignment
    __shared__ float zt[TPX * ZSTR];
    const int b  = blockIdx.x / (N / TPX);
    const int n0 = (blockIdx.x % (N / TPX)) * TPX;
    const int tid = threadIdx.x;

    for (int idx = tid; idx < COUT * TPX; idx += BS) {
        int c = idx / TPX, px = idx % TPX;
        int n = n0 + px;
        int ho = n / HOUT, wo = n % HOUT;
        float a0 = cb[c], a1 = 0.f, a2 = 0.f;     // 3-way ILP over kh
        for (int ci = 0; ci < CIN; ++ci) {
            const float* ip = in + (size_t)(b * CIN + ci) * HIN * HIN;
            const float* wp = cw + (size_t)(c * CIN + ci) * 9;
            #pragma unroll
            for (int kh = 0; kh < 3; ++kh) {
                int hi = 2 * ho + kh - 1;
                if (hi < 0 || hi >= HIN) continue;
                float av = 0.f;
                #pragma unroll
                for (int kw = 0; kw < 3; ++kw) {
                    int wi = 2 * wo + kw - 1;
                    if (wi < 0 || wi >= HIN) continue;
                    av = fmaf(wp[kh * 3 + kw], ip[hi * HIN + wi], av);
                }
                if (kh == 0) a0 += av; else if (kh == 1) a1 += av; else a2 += av;
            }
        }
        float acc = fmaxf((a0 + a1) + a2, 0.f);
        zt[px * ZSTR + c] = acc;
        z[((size_t)(b * COUT) + c) * N + n] = acc;
    }
    __syncthreads();

    constexpr int OC3 = 3 * INNER;
    constexpr int NF4 = COUT / 4;
    for (int idx = tid; idx < OC3 * TPX; idx += BS) {
        int oc = idx / TPX, px = idx % TPX;
        const float4* wp4 = (const float4*)(qw + (size_t)oc * COUT);
        const float4* z4  = (const float4*)(zt + px * ZSTR);
        float vs[4] = {0.f, 0.f, 0.f, 0.f};
        #pragma unroll
        for (int c4 = 0; c4 < NF4; ++c4) {
            float4 a = wp4[c4], bb = z4[c4];
            float& v = vs[c4 & 3];
            v = fmaf(a.x, bb.x, v); v = fmaf(a.y, bb.y, v);
            v = fmaf(a.z, bb.z, v); v = fmaf(a.w, bb.w, v);
        }
        float val = qb[oc] + ((vs[0] + vs[1]) + (vs[2] + vs[3]));
        int part = oc / INNER;
        int r = oc - part * INNER;
        int hh = r % 3, dd = r / 3;  // heads fastest
        size_t n = n0 + px;
        if (part == 0)
            q[((size_t)(b * 3 + hh) * N + n) * DP + dd] = val;
        else
            kv[((size_t)(b * 3 + hh) * N + n) * KVRS + (part - 1) * KVD + dd] = val;
    }
}

// ---------- fused: prev outproj(+residual) halo -> conv3x3 s2 relu -> qkv ----------
template <int CPREV, int INNERP, int DPREV, int HINW, int COUT, int HOUT, int INNER, int DP,
          int KVRS, int KVD, int TPX, int BS>
__global__ void __launch_bounds__(BS) fused_oc(const float* __restrict__ o1,
                                               const float* __restrict__ ow,
                                               const float* __restrict__ ob,
                                               const float* __restrict__ zres,
                                               const float* __restrict__ cw,
                                               const float* __restrict__ cb,
                                               const float* __restrict__ qw,
                                               const float* __restrict__ qb,
                                               float* __restrict__ z, float* __restrict__ q,
                                               float* __restrict__ kv) {
    constexpr int N2 = HOUT * HOUT;
    constexpr int N1 = HINW * HINW;
    constexpr int TROWS = TPX / HOUT;     // output rows per tile
    constexpr int HR = 2 * TROWS + 1;     // halo input rows
    constexpr int HALO = HR * HINW;
    constexpr int ZSTR = COUT + 4;
    __shared__ float smem[INNERP * HALO + CPREV * HALO];
    float* o1s = smem;                    // INNERP*HALO (phase 0 only)
    float* zh  = smem + INNERP * HALO;    // CPREV*HALO
    float* zt  = smem;                    // TPX*ZSTR, overlays o1s after phase 0b
    static_assert(TPX * ZSTR <= INNERP * HALO, "zt overlay fits");
    const int b  = blockIdx.x / (N2 / TPX);
    const int n0 = (blockIdx.x % (N2 / TPX)) * TPX;
    const int tid = threadIdx.x;
    const int ho0 = n0 / HOUT;
    const int row0 = 2 * ho0 - 1;

    // phase 0a: stage o1 halo slice (coalesced)
    for (int t = tid; t < INNERP * HALO; t += BS) {
        int hd = t / HALO, p = t - hd * HALO;
        int row = row0 + p / HINW;
        float v = 0.f;
        if (row >= 0 && row < HINW)
            v = o1[((size_t)(b * INNERP + hd)) * N1 + row * HINW + (p % HINW)];
        o1s[t] = v;
    }
    __syncthreads();

    // phase 0b: outproj + bias + residual for the halo -> zh (3-way ILP over hh)
    for (int t = tid; t < CPREV * HALO; t += BS) {
        int ci = t / HALO, p = t - ci * HALO;
        int row = row0 + p / HINW;
        float val = 0.f;  // conv zero-padding
        if (row >= 0 && row < HINW) {
            int n1 = row * HINW + (p % HINW);
            const float* wp = ow + (size_t)ci * INNERP;
            float v0 = 0.f, v1 = 0.f, v2 = 0.f;
            for (int dd = 0; dd < DPREV; ++dd) {
                v0 = fmaf(wp[dd * 3 + 0], o1s[(0 * DPREV + dd) * HALO + p], v0);
                v1 = fmaf(wp[dd * 3 + 1], o1s[(1 * DPREV + dd) * HALO + p], v1);
                v2 = fmaf(wp[dd * 3 + 2], o1s[(2 * DPREV + dd) * HALO + p], v2);
            }
            val = ob[ci] + zres[((size_t)(b * CPREV) + ci) * N1 + n1] + (v0 + v1) + v2;
        }
        zh[t] = val;
    }
    __syncthreads();

    // phase 1: conv from LDS halo (+ relu); 3-way ILP over kh; zt transposed+padded
    for (int idx = tid; idx < COUT * TPX; idx += BS) {
        int c = idx / TPX, px = idx - (idx / TPX) * TPX;
        int hol = px / HOUT, wo = px - hol * HOUT;
        float a0 = cb[c], a1 = 0.f, a2 = 0.f;
        for (int ci = 0; ci < CPREV; ++ci) {
            const float* zp = zh + ci * HALO + (2 * hol) * HINW;
            const float* wp = cw + (size_t)(c * CPREV + ci) * 9;
            #pragma unroll
            for (int kw = 0; kw < 3; ++kw) {
                int col = 2 * wo + kw - 1;
                if (col < 0 || col >= HINW) continue;
                a0 = fmaf(wp[0 * 3 + kw], zp[0 * HINW + col], a0);
                a1 = fmaf(wp[1 * 3 + kw], zp[1 * HINW + col], a1);
                a2 = fmaf(wp[2 * 3 + kw], zp[2 * HINW + col], a2);
            }
        }
        float acc = fmaxf((a0 + a1) + a2, 0.f);
        zt[px * ZSTR + c] = acc;
        z[((size_t)(b * COUT) + c) * N2 + n0 + px] = acc;
    }
    __syncthreads();

    // phase 2: qkv from LDS tile (float4 LDS reads + 4 partial accumulators)
    constexpr int OC3 = 3 * INNER;
    constexpr int NF4 = COUT / 4;
    for (int idx = tid; idx < OC3 * TPX; idx += BS) {
        int oc = idx / TPX, px = idx % TPX;
        const float4* wp4 = (const float4*)(qw + (size_t)oc * COUT);
        const float4* z4  = (const float4*)(zt + px * ZSTR);
        float vs[4] = {0.f, 0.f, 0.f, 0.f};
        #pragma unroll
        for (int c4 = 0; c4 < NF4; ++c4) {
            float4 a = wp4[c4], bb = z4[c4];
            float& v = vs[c4 & 3];
            v = fmaf(a.x, bb.x, v); v = fmaf(a.y, bb.y, v);
            v = fmaf(a.z, bb.z, v); v = fmaf(a.w, bb.w, v);
        }
        float val = qb[oc] + ((vs[0] + vs[1]) + (vs[2] + vs[3]));
        int part = oc / INNER;
        int r = oc - part * INNER;
        int hh = r % 3, dd = r / 3;  // heads fastest
        size_t n = n0 + px;
        if (part == 0)
            q[((size_t)(b * 3 + hh) * N2 + n) * DP + dd] = val;
        else
            kv[((size_t)(b * 3 + hh) * N2 + n) * KVRS + (part - 1) * KVD + dd] = val;
    }
}

// ---------- attention (L1/L2): R6 config + SALU uniform math + 8j unrolled bodies ----------
// KV staged by global_load_lds DMA into wave-private LDS buffer(s); j-loop reads K/V via
// conflict-free LDS broadcasts; flat cross-wave combine. `wave` readfirstlane-pinned (R15:
// -4.4us). jg-loop unrolled x2 (8 j per body): more KV ds_read offsets fold into offset:
// immediates off one base VGPR, trimming per-j address VALU. No added loop-carried state
// (spill-safe, unlike R8/R13).
template <int D, int QP, int RS, int RPT, int TILE, int NW, int NBUF>
__global__ void __launch_bounds__(NW * 64) attn_big(const float* __restrict__ q,
                                                    const float* __restrict__ kv,
                                                    const float* __restrict__ table,
                                                    float* __restrict__ o, int N, int log2Hg,
                                                    int T, float scale2) {
    extern __shared__ float smem[];
    float* tb = smem;       // T floats, pre-scaled by scale2 (incl. log2e)
    float* comb = smem;     // overlays tb + kv tiles after j-loop
    constexpr int BT = NW * 64;
    constexpr int ROWS = 64 * RPT;
    constexpr int CSTR = (D % 2 == 0) ? (D + 3) : (D + 2);
    constexpr int TBYTES = TILE * RS * 4;          // bytes per tile
    constexpr int LPT = CDIV(TBYTES, 1024);        // global_load_lds calls per tile
    constexpr bool FULLT = (TBYTES % 1024) == 0;
    static_assert(LPT == 3, "vmcnt literal below assumes 3 loads per tile");

    const int bh = blockIdx.x % 96;
    const int chunk = blockIdx.x / 96;
    const int h = bh % 3;
    const int tid = threadIdx.x;
    const int wave = __builtin_amdgcn_readfirstlane(tid >> 6);  // wave-uniform -> SGPR
    const int lane = tid & 63;
    const int Hg = 1 << log2Hg;
    const int W2 = 2 * Hg - 1;
    const int base = chunk * ROWS;

    // wave-private KV tile buffer(s) (16B-aligned offset past tb)
    float* kvw = smem + ((T + 3) & ~3) + wave * (NBUF * TILE * RS);

    for (int t = tid; t < T; t += BT) tb[t] = table[t * 3 + h] * scale2;

    float qr[RPT][D];
    const float* tbp[RPT];  // per-lane bias row base: tb + ibase[r]
    #pragma unroll
    for (int r = 0; r < RPT; ++r) {
        int i = base + lane + 64 * r;
        const float* qg = q + ((size_t)bh * N + i) * QP;
        #pragma unroll
        for (int dd = 0; dd < D; ++dd) qr[r][dd] = qg[dd];
        tbp[r] = tb + (((i >> log2Hg) + Hg - 1) * W2 + (i & (Hg - 1)) + Hg - 1);
    }

    float acc[RPT][D];
    float lsum[RPT];
    #pragma unroll
    for (int r = 0; r < RPT; ++r) {
        lsum[r] = 0.f;
        #pragma unroll
        for (int dd = 0; dd < D; ++dd) acc[r][dd] = 0.f;
    }

    const float* kvbase = kv + (size_t)bh * N * RS;
    const int NJ = N / NW;
    const int NT = NJ / TILE;
    const int j0 = wave * NJ;

    // DMA one tile into LDS buffer bufIdx (wave-uniform LDS base + lane*16 linear)
    auto stage = [&](int bufIdx, int t) {
        const float* srcf = kvbase + (size_t)(j0 + t * TILE) * RS;
        float* dstf = kvw + bufIdx * (TILE * RS);
        #pragma unroll
        for (int x = 0; x < LPT; ++x) {
            if (FULLT || (x * 1024 + lane * 16) < TBYTES) {
                const void* g = (const void*)(srcf + x * 256 + lane * 4);
                void* l = (void*)(dstf + x * 256);
                __builtin_amdgcn_global_load_lds(
                    (const __attribute__((address_space(1))) void*)g,
                    (__attribute__((address_space(3))) void*)l, 16, 0, 0);
            }
        }
    };

    // prologue: stage tiles 0 and 1; the tb barrier below drains them (vmcnt(0))
    stage(0, 0);
    if (NBUF > 1 && NT > 1) stage(1, 1);

    __syncthreads();  // tb staged + prologue DMA complete

    for (int t = 0; t < NT; ++t) {
        const float* curb = kvw + (t & (NBUF - 1)) * (TILE * RS);
        const int jt = j0 + t * TILE;
        #pragma unroll 2
        for (int jg = 0; jg < TILE; jg += 4) {
            #pragma unroll
            for (int k = 0; k < 4; ++k) {
                const int j = jt + jg + k;
                const float* kr = curb + (jg + k) * RS;  // wave-uniform LDS broadcast
                const int joff = (j >> log2Hg) * W2 + (j & (Hg - 1));
                #pragma unroll
                for (int r = 0; r < RPT; ++r) {
                    float s = 0.f;
                    #pragma unroll
                    for (int dd = 0; dd < D; ++dd) s = fmaf(qr[r][dd], kr[dd], s);
                    float e = EXP2(fmaf(s, scale2, tbp[r][-joff]));
                    lsum[r] += e;
                    #pragma unroll
                    for (int dd = 0; dd < D; ++dd) acc[r][dd] = fmaf(e, kr[D + dd], acc[r][dd]);
                }
            }
        }
        if (NBUF > 1 && t + 2 < NT) {
            // all reads of buf[t&1] done (DS in-order) before DMA may overwrite it
            asm volatile("s_waitcnt lgkmcnt(0)" ::: "memory");
            stage(t & 1, t + 2);
            waitcnt_vm<3>();   // tile t+1 resident; tile t+2's 3 loads stay in flight
        } else if (NBUF > 1 && t + 1 < NT) {
            waitcnt_vm<0>();   // last tile: drain
        }
    }

    __syncthreads();
    #pragma unroll
    for (int r = 0; r < RPT; ++r) {
        float* cp = comb + (size_t)(wave * ROWS + lane + 64 * r) * CSTR;
        #pragma unroll
        for (int dd = 0; dd < D; ++dd) cp[dd] = acc[r][dd];
        cp[D] = lsum[r];
    }
    __syncthreads();
    if (tid < ROWS) {
        float af[D];
        #pragma unroll
        for (int dd = 0; dd < D; ++dd) af[dd] = 0.f;
        float lf = 0.f;
        #pragma unroll
        for (int wv = 0; wv < NW; ++wv) {
            const float* cp = comb + (size_t)(wv * ROWS + tid) * CSTR;
            #pragma unroll
            for (int dd = 0; dd < D; ++dd) af[dd] += cp[dd];
            lf += cp[D];
        }
        float inv = 1.0f / lf;
        int i = base + tid;
        #pragma unroll
        for (int dd = 0; dd < D; ++dd)
            o[((size_t)bh * D + dd) * N + i] = af[dd] * inv;  // O layout [bh][d][N]
    }
}

// ---------- L3 attention: one block per bh; KV+table staged in LDS; 8-wave j-split ----------
__global__ void __launch_bounds__(512) attn_small(const float* __restrict__ q,
                                                  const float* __restrict__ kv,
                                                  const float* __restrict__ table,
                                                  float* __restrict__ o, float scale2) {
    constexpr int D = 21, DP = 24, NN = 64;
    constexpr int CSTR = 23;
    __shared__ float smem[8 * NN * CSTR];  // 47104 B; comb overlays kvs/tb
    float* kvs = smem;
    float* tb = kvs + NN * 2 * DP;
    float* comb = smem;

    const int bh = blockIdx.x;     // 96 blocks
    const int h = bh % 3;
    const int tid = threadIdx.x;
    const int wave = __builtin_amdgcn_readfirstlane(tid >> 6);
    const int lane = tid & 63;

    {
        const float4* kvg = (const float4*)(kv + (size_t)bh * NN * 2 * DP);
        float4* kvs4 = (float4*)kvs;
        for (int t = tid; t < NN * 2 * DP / 4; t += 512) kvs4[t] = kvg[t];
        for (int t = tid; t < 225; t += 512) tb[t] = table[t * 3 + h] * scale2;
    }

    const int i = lane;
    const float* qg = q + ((size_t)bh * NN + i) * DP;
    float qr[D];
    #pragma unroll
    for (int dd = 0; dd < D; ++dd) qr[dd] = qg[dd];
    const int ibase = ((i >> 3) + 7) * 15 + (i & 7) + 7;
    __syncthreads();

    float acc[D];
    #pragma unroll
    for (int dd = 0; dd < D; ++dd) acc[dd] = 0.f;
    float lsum = 0.f;

    const int j0 = wave * 8;   // 8 waves x 8 js
    #pragma unroll
    for (int jj = 0; jj < 8; ++jj) {
        const int j = j0 + jj;
        float4 r4[12];
        const float4* rp = (const float4*)(kvs + j * 2 * DP);
        #pragma unroll
        for (int x = 0; x < 12; ++x) r4[x] = rp[x];
        const float* kr = (const float*)r4;
        const float* vr = kr + DP;
        const int joff = (j >> 3) * 15 + (j & 7);
        float s = 0.f;
        #pragma unroll
        for (int dd = 0; dd < D; ++dd) s = fmaf(qr[dd], kr[dd], s);
        float e = EXP2(fmaf(s, scale2, tb[ibase - joff]));
        lsum += e;
        #pragma unroll
        for (int dd = 0; dd < D; ++dd) acc[dd] = fmaf(e, vr[dd], acc[dd]);
    }

    __syncthreads();
    {
        float* cp = comb + (size_t)(wave * NN + lane) * CSTR;
        #pragma unroll
        for (int dd = 0; dd < D; ++dd) cp[dd] = acc[dd];
        cp[D] = lsum;
    }
    __syncthreads();
    if (tid < NN) {
        float af[D];
        #pragma unroll
        for (int dd = 0; dd < D; ++dd) af[dd] = 0.f;
        float lf = 0.f;
        #pragma unroll
        for (int wv = 0; wv < 8; ++wv) {
            const float* cp = comb + (size_t)(wv * NN + tid) * CSTR;
            #pragma unroll
            for (int dd = 0; dd < D; ++dd) af[dd] += cp[dd];
            lf += cp[D];
        }
        float inv = 1.0f / lf;
        #pragma unroll
        for (int dd = 0; dd < D; ++dd)
            o[((size_t)bh * D + dd) * NN + tid] = af[dd] * inv;
    }
}

// ---------- tail: outproj3 + global-avg-pool + classifier (3-way ILP over hh) ----------
__global__ void __launch_bounds__(256) tail(const float* __restrict__ o,
                                            const float* __restrict__ ow,
                                            const float* __restrict__ ob,
                                            const float* __restrict__ zin,
                                            const float* __restrict__ cw,
                                            const float* __restrict__ cb,
                                            float* __restrict__ out) {
    __shared__ float os[63 * 64];
    __shared__ float zt[64 * 65];
    __shared__ float p[64];
    const int b = blockIdx.x;
    const int tid = threadIdx.x;
    // stage o[b]: rows b*63..b*63+62 are contiguous (layout [bh][d][N], hd = hh*21+dd)
    for (int t = tid; t < 63 * 64; t += 256) os[t] = o[(size_t)(b * 63) * 64 + t];
    __syncthreads();
    for (int idx = tid; idx < 64 * 64; idx += 256) {
        int c = idx >> 6, n = idx & 63;
        const float* wp = ow + (size_t)c * 63;
        float v0 = 0.f, v1 = 0.f, v2 = 0.f;
        for (int dd = 0; dd < 21; ++dd) {
            v0 = fmaf(wp[dd * 3 + 0], os[(0  + dd) * 64 + n], v0);
            v1 = fmaf(wp[dd * 3 + 1], os[(21 + dd) * 64 + n], v1);
            v2 = fmaf(wp[dd * 3 + 2], os[(42 + dd) * 64 + n], v2);
        }
        zt[c * 65 + n] = ob[c] + zin[((size_t)(b * 64) + c) * 64 + n] + (v0 + v1) + v2;
    }
    __syncthreads();
    if (tid < 64) {
        float s = 0.f;
        #pragma unroll
        for (int n = 0; n < 64; ++n) s += zt[tid * 65 + n];
        s *= (1.0f / 64.0f);
        p[tid] = s;
        out[b * 64 + tid] = s;
    }
    __syncthreads();
    if (tid < 10) {
        float val = cb[tid];
        const float* wp = cw + (size_t)tid * 64;
        #pragma unroll
        for (int kk = 0; kk < 64; ++kk) val = fmaf(wp[kk], p[kk], val);
        out[2048 + b * 10 + tid] = val;
    }
}

extern "C" void kernel_launch(void* const* d_in, const int* in_sizes, int n_in,
                              void* d_out, int out_size, void* d_ws, size_t ws_size,
                              hipStream_t stream) {
    float* ws = (float*)d_ws;
    float* Zc1 = ws;                 // conv1 z (524288) / later conv3 z (131072)
    float* Zc2 = Zc1 + 524288;       // conv2 z (262144)
    float* Q   = Zc2 + 262144;       // 786432 (96*1024*8 max)
    float* KV  = Q + 786432;         // 1572864 region (L1 packed uses 96*1024*12)
    float* O   = KV + 1572864;       // 491520 (96*1024*5 max)

    float* out = (float*)d_out;

    // ===== layer 1: Cin=1 H64->32, dim=16, inner=15, d=5 (q pad 8, kv stride 12), N=1024 =====
    conv_qkv<1, 64, 16, 32, 15, 8, 12, 5, 32, 512><<<32 * 32, 512, 0, stream>>>(
        (const float*)d_in[0], (const float*)d_in[1], (const float*)d_in[2],
        (const float*)d_in[3], (const float*)d_in[4], Zc1, Q, KV);
    // R6 shape + SALU wave pin + 8j-unrolled bodies: RPT=2, NW=4, TILE=64, NBUF=2
    attn_big<5, 8, 12, 2, 64, 4, 2><<<96 * 8, 256, 40464, stream>>>(
        Q, KV, (const float*)d_in[7], O, 1024, 5, 3969, SC5);

    // ===== layer 2 (fused outproj1 + conv2 + qkv2): dim=32, d=10 (q pad 12, kv stride 20), N=256 =====
    fused_oc<16, 15, 5, 32, 32, 16, 30, 12, 20, 10, 16, 512><<<32 * 16, 512, 0, stream>>>(
        O, (const float*)d_in[5], (const float*)d_in[6], Zc1,
        (const float*)d_in[8], (const float*)d_in[9],
        (const float*)d_in[10], (const float*)d_in[11], Zc2, Q, KV);
    // NW=8, RPT=1, TILE=32, NBUF=1 (NT=1); smem = max(964+8*32*20, comb 8*64*13)*4 = 26624 B
    attn_big<10, 12, 20, 1, 32, 8, 1><<<96 * 4, 512, 26624, stream>>>(
        Q, KV, (const float*)d_in[14], O, 256, 4, 961, SC10);

    // ===== layer 3 (fused outproj2 + conv3 + qkv3): dim=64, d=21 (DP=24, kv interleaved 48) =====
    fused_oc<32, 30, 10, 16, 64, 8, 63, 24, 48, 24, 8, 512><<<32 * 8, 512, 0, stream>>>(
        O, (const float*)d_in[12], (const float*)d_in[13], Zc2,
        (const float*)d_in[15], (const float*)d_in[16],
        (const float*)d_in[17], (const float*)d_in[18], Zc1, Q, KV);
    attn_small<<<96, 512, 0, stream>>>(Q, KV, (const float*)d_in[21], O, SC21);

    // ===== head =====
    tail<<<32, 256, 0, stream>>>(
        O, (const float*)d_in[19], (const float*)d_in[20], Zc1,
        (const float*)d_in[22], (const float*)d_in[23], out);
}

// Round 17
// 239.856 us; speedup vs baseline: 2.0167x; 1.0169x over previous
//
#include <hip/hip_runtime.h>
#include <math.h>

#define CDIV(a, b) (((a) + (b) - 1) / (b))

#define LOG2E 1.4426950408889634f
#define SC5  (0.44721359549996f * LOG2E)
#define SC10 (0.31622776601684f * LOG2E)
#define SC21 (0.21821789023599f * LOG2E)
#define EXP2(x) __builtin_amdgcn_exp2f(x)

template <int N> __device__ inline void waitcnt_vm() {
    if constexpr (N == 0) asm volatile("s_waitcnt vmcnt(0)" ::: "memory");
    else if constexpr (N == 3) asm volatile("s_waitcnt vmcnt(3)" ::: "memory");
    else static_assert(N < 0, "unsupported vmcnt literal");
}

// ---------- fused 3x3 s2 conv + relu + qkv projection (layer 1 only) ----------
// zt stored TRANSPOSED+padded [px][COUT+4] so phase-2 reads are float4 LDS loads.
template <int CIN, int HIN, int COUT, int HOUT, int INNER, int DP, int KVRS, int KVD, int TPX,
          int BS>
__global__ void __launch_bounds__(BS) conv_qkv(const float* __restrict__ in,
                                               const float* __restrict__ cw,
                                               const float* __restrict__ cb,
                                               const float* __restrict__ qw,
                                               const float* __restrict__ qb,
                                               float* __restrict__ z, float* __restrict__ q,
                                               float* __restrict__ kv) {
    constexpr int N = HOUT * HOUT;
    constexpr int ZSTR = COUT + 4;          // pad: bank spread + keeps 16B alignment
    __shared__ float zt[TPX * ZSTR];
    const int b  = blockIdx.x / (N / TPX);
    const int n0 = (blockIdx.x % (N / TPX)) * TPX;
    const int tid = threadIdx.x;

    for (int idx = tid; idx < COUT * TPX; idx += BS) {
        int c = idx / TPX, px = idx % TPX;
        int n = n0 + px;
        int ho = n / HOUT, wo = n % HOUT;
        float a0 = cb[c], a1 = 0.f, a2 = 0.f;     // 3-way ILP over kh
        for (int ci = 0; ci < CIN; ++ci) {
            const float* ip = in + (size_t)(b * CIN + ci) * HIN * HIN;
            const float* wp = cw + (size_t)(c * CIN + ci) * 9;
            #pragma unroll
            for (int kh = 0; kh < 3; ++kh) {
                int hi = 2 * ho + kh - 1;
                if (hi < 0 || hi >= HIN) continue;
                float av = 0.f;
                #pragma unroll
                for (int kw = 0; kw < 3; ++kw) {
                    int wi = 2 * wo + kw - 1;
                    if (wi < 0 || wi >= HIN) continue;
                    av = fmaf(wp[kh * 3 + kw], ip[hi * HIN + wi], av);
                }
                if (kh == 0) a0 += av; else if (kh == 1) a1 += av; else a2 += av;
            }
        }
        float acc = fmaxf((a0 + a1) + a2, 0.f);
        zt[px * ZSTR + c] = acc;
        z[((size_t)(b * COUT) + c) * N + n] = acc;
    }
    __syncthreads();

    constexpr int OC3 = 3 * INNER;
    constexpr int NF4 = COUT / 4;
    for (int idx = tid; idx < OC3 * TPX; idx += BS) {
        int oc = idx / TPX, px = idx % TPX;
        const float4* wp4 = (const float4*)(qw + (size_t)oc * COUT);
        const float4* z4  = (const float4*)(zt + px * ZSTR);
        float vs[4] = {0.f, 0.f, 0.f, 0.f};
        #pragma unroll
        for (int c4 = 0; c4 < NF4; ++c4) {
            float4 a = wp4[c4], bb = z4[c4];
            float& v = vs[c4 & 3];
            v = fmaf(a.x, bb.x, v); v = fmaf(a.y, bb.y, v);
            v = fmaf(a.z, bb.z, v); v = fmaf(a.w, bb.w, v);
        }
        float val = qb[oc] + ((vs[0] + vs[1]) + (vs[2] + vs[3]));
        int part = oc / INNER;
        int r = oc - part * INNER;
        int hh = r % 3, dd = r / 3;  // heads fastest
        size_t n = n0 + px;
        if (part == 0)
            q[((size_t)(b * 3 + hh) * N + n) * DP + dd] = val;
        else
            kv[((size_t)(b * 3 + hh) * N + n) * KVRS + (part - 1) * KVD + dd] = val;
    }
}

// ---------- fused: prev outproj(+residual) halo -> conv3x3 s2 relu -> qkv ----------
template <int CPREV, int INNERP, int DPREV, int HINW, int COUT, int HOUT, int INNER, int DP,
          int KVRS, int KVD, int TPX, int BS>
__global__ void __launch_bounds__(BS) fused_oc(const float* __restrict__ o1,
                                               const float* __restrict__ ow,
                                               const float* __restrict__ ob,
                                               const float* __restrict__ zres,
                                               const float* __restrict__ cw,
                                               const float* __restrict__ cb,
                                               const float* __restrict__ qw,
                                               const float* __restrict__ qb,
                                               float* __restrict__ z, float* __restrict__ q,
                                               float* __restrict__ kv) {
    constexpr int N2 = HOUT * HOUT;
    constexpr int N1 = HINW * HINW;
    constexpr int TROWS = TPX / HOUT;     // output rows per tile
    constexpr int HR = 2 * TROWS + 1;     // halo input rows
    constexpr int HALO = HR * HINW;
    constexpr int ZSTR = COUT + 4;
    __shared__ float smem[INNERP * HALO + CPREV * HALO];
    float* o1s = smem;                    // INNERP*HALO (phase 0 only)
    float* zh  = smem + INNERP * HALO;    // CPREV*HALO
    float* zt  = smem;                    // TPX*ZSTR, overlays o1s after phase 0b
    static_assert(TPX * ZSTR <= INNERP * HALO, "zt overlay fits");
    const int b  = blockIdx.x / (N2 / TPX);
    const int n0 = (blockIdx.x % (N2 / TPX)) * TPX;
    const int tid = threadIdx.x;
    const int ho0 = n0 / HOUT;
    const int row0 = 2 * ho0 - 1;

    // phase 0a: stage o1 halo slice (coalesced)
    for (int t = tid; t < INNERP * HALO; t += BS) {
        int hd = t / HALO, p = t - hd * HALO;
        int row = row0 + p / HINW;
        float v = 0.f;
        if (row >= 0 && row < HINW)
            v = o1[((size_t)(b * INNERP + hd)) * N1 + row * HINW + (p % HINW)];
        o1s[t] = v;
    }
    __syncthreads();

    // phase 0b: outproj + bias + residual for the halo -> zh (3-way ILP over hh)
    for (int t = tid; t < CPREV * HALO; t += BS) {
        int ci = t / HALO, p = t - ci * HALO;
        int row = row0 + p / HINW;
        float val = 0.f;  // conv zero-padding
        if (row >= 0 && row < HINW) {
            int n1 = row * HINW + (p % HINW);
            const float* wp = ow + (size_t)ci * INNERP;
            float v0 = 0.f, v1 = 0.f, v2 = 0.f;
            for (int dd = 0; dd < DPREV; ++dd) {
                v0 = fmaf(wp[dd * 3 + 0], o1s[(0 * DPREV + dd) * HALO + p], v0);
                v1 = fmaf(wp[dd * 3 + 1], o1s[(1 * DPREV + dd) * HALO + p], v1);
                v2 = fmaf(wp[dd * 3 + 2], o1s[(2 * DPREV + dd) * HALO + p], v2);
            }
            val = ob[ci] + zres[((size_t)(b * CPREV) + ci) * N1 + n1] + (v0 + v1) + v2;
        }
        zh[t] = val;
    }
    __syncthreads();

    // phase 1: conv from LDS halo (+ relu); 3-way ILP over kh; zt transposed+padded
    for (int idx = tid; idx < COUT * TPX; idx += BS) {
        int c = idx / TPX, px = idx - (idx / TPX) * TPX;
        int hol = px / HOUT, wo = px - hol * HOUT;
        float a0 = cb[c], a1 = 0.f, a2 = 0.f;
        for (int ci = 0; ci < CPREV; ++ci) {
            const float* zp = zh + ci * HALO + (2 * hol) * HINW;
            const float* wp = cw + (size_t)(c * CPREV + ci) * 9;
            #pragma unroll
            for (int kw = 0; kw < 3; ++kw) {
                int col = 2 * wo + kw - 1;
                if (col < 0 || col >= HINW) continue;
                a0 = fmaf(wp[0 * 3 + kw], zp[0 * HINW + col], a0);
                a1 = fmaf(wp[1 * 3 + kw], zp[1 * HINW + col], a1);
                a2 = fmaf(wp[2 * 3 + kw], zp[2 * HINW + col], a2);
            }
        }
        float acc = fmaxf((a0 + a1) + a2, 0.f);
        zt[px * ZSTR + c] = acc;
        z[((size_t)(b * COUT) + c) * N2 + n0 + px] = acc;
    }
    __syncthreads();

    // phase 2: qkv from LDS tile (float4 LDS reads + 4 partial accumulators)
    constexpr int OC3 = 3 * INNER;
    constexpr int NF4 = COUT / 4;
    for (int idx = tid; idx < OC3 * TPX; idx += BS) {
        int oc = idx / TPX, px = idx % TPX;
        const float4* wp4 = (const float4*)(qw + (size_t)oc * COUT);
        const float4* z4  = (const float4*)(zt + px * ZSTR);
        float vs[4] = {0.f, 0.f, 0.f, 0.f};
        #pragma unroll
        for (int c4 = 0; c4 < NF4; ++c4) {
            float4 a = wp4[c4], bb = z4[c4];
            float& v = vs[c4 & 3];
            v = fmaf(a.x, bb.x, v); v = fmaf(a.y, bb.y, v);
            v = fmaf(a.z, bb.z, v); v = fmaf(a.w, bb.w, v);
        }
        float val = qb[oc] + ((vs[0] + vs[1]) + (vs[2] + vs[3]));
        int part = oc / INNER;
        int r = oc - part * INNER;
        int hh = r % 3, dd = r / 3;  // heads fastest
        size_t n = n0 + px;
        if (part == 0)
            q[((size_t)(b * 3 + hh) * N2 + n) * DP + dd] = val;
        else
            kv[((size_t)(b * 3 + hh) * N2 + n) * KVRS + (part - 1) * KVD + dd] = val;
    }
}

// ---------- attention (L1/L2): SALU uniform math; per-instantiation unroll ----------
// KV staged by global_load_lds DMA into wave-private LDS buffer(s); j-loop reads K/V via
// conflict-free LDS broadcasts; flat cross-wave combine. `wave` readfirstlane-pinned (R15:
// -4.4us). UNR split per R16 A/B: L1 (TILE=64) best at 4-j cadence (UNR=1); L2 (TILE=32,
// NT=1) gains ~3us from the flattened 8-j body (UNR=2).
template <int D, int QP, int RS, int RPT, int TILE, int NW, int NBUF, int UNR>
__global__ void __launch_bounds__(NW * 64) attn_big(const float* __restrict__ q,
                                                    const float* __restrict__ kv,
                                                    const float* __restrict__ table,
                                                    float* __restrict__ o, int N, int log2Hg,
                                                    int T, float scale2) {
    extern __shared__ float smem[];
    float* tb = smem;       // T floats, pre-scaled by scale2 (incl. log2e)
    float* comb = smem;     // overlays tb + kv tiles after j-loop
    constexpr int BT = NW * 64;
    constexpr int ROWS = 64 * RPT;
    constexpr int CSTR = (D % 2 == 0) ? (D + 3) : (D + 2);
    constexpr int TBYTES = TILE * RS * 4;          // bytes per tile
    constexpr int LPT = CDIV(TBYTES, 1024);        // global_load_lds calls per tile
    constexpr bool FULLT = (TBYTES % 1024) == 0;
    static_assert(LPT == 3, "vmcnt literal below assumes 3 loads per tile");

    const int bh = blockIdx.x % 96;
    const int chunk = blockIdx.x / 96;
    const int h = bh % 3;
    const int tid = threadIdx.x;
    const int wave = __builtin_amdgcn_readfirstlane(tid >> 6);  // wave-uniform -> SGPR
    const int lane = tid & 63;
    const int Hg = 1 << log2Hg;
    const int W2 = 2 * Hg - 1;
    const int base = chunk * ROWS;

    // wave-private KV tile buffer(s) (16B-aligned offset past tb)
    float* kvw = smem + ((T + 3) & ~3) + wave * (NBUF * TILE * RS);

    for (int t = tid; t < T; t += BT) tb[t] = table[t * 3 + h] * scale2;

    float qr[RPT][D];
    const float* tbp[RPT];  // per-lane bias row base: tb + ibase[r]
    #pragma unroll
    for (int r = 0; r < RPT; ++r) {
        int i = base + lane + 64 * r;
        const float* qg = q + ((size_t)bh * N + i) * QP;
        #pragma unroll
        for (int dd = 0; dd < D; ++dd) qr[r][dd] = qg[dd];
        tbp[r] = tb + (((i >> log2Hg) + Hg - 1) * W2 + (i & (Hg - 1)) + Hg - 1);
    }

    float acc[RPT][D];
    float lsum[RPT];
    #pragma unroll
    for (int r = 0; r < RPT; ++r) {
        lsum[r] = 0.f;
        #pragma unroll
        for (int dd = 0; dd < D; ++dd) acc[r][dd] = 0.f;
    }

    const float* kvbase = kv + (size_t)bh * N * RS;
    const int NJ = N / NW;
    const int NT = NJ / TILE;
    const int j0 = wave * NJ;

    // DMA one tile into LDS buffer bufIdx (wave-uniform LDS base + lane*16 linear)
    auto stage = [&](int bufIdx, int t) {
        const float* srcf = kvbase + (size_t)(j0 + t * TILE) * RS;
        float* dstf = kvw + bufIdx * (TILE * RS);
        #pragma unroll
        for (int x = 0; x < LPT; ++x) {
            if (FULLT || (x * 1024 + lane * 16) < TBYTES) {
                const void* g = (const void*)(srcf + x * 256 + lane * 4);
                void* l = (void*)(dstf + x * 256);
                __builtin_amdgcn_global_load_lds(
                    (const __attribute__((address_space(1))) void*)g,
                    (__attribute__((address_space(3))) void*)l, 16, 0, 0);
            }
        }
    };

    // prologue: stage tiles 0 and 1; the tb barrier below drains them (vmcnt(0))
    stage(0, 0);
    if (NBUF > 1 && NT > 1) stage(1, 1);

    __syncthreads();  // tb staged + prologue DMA complete

    for (int t = 0; t < NT; ++t) {
        const float* curb = kvw + (t & (NBUF - 1)) * (TILE * RS);
        const int jt = j0 + t * TILE;
        auto group = [&](int jg) {
            #pragma unroll
            for (int k = 0; k < 4; ++k) {
                const int j = jt + jg + k;
                const float* kr = curb + (jg + k) * RS;  // wave-uniform LDS broadcast
                const int joff = (j >> log2Hg) * W2 + (j & (Hg - 1));
                #pragma unroll
                for (int r = 0; r < RPT; ++r) {
                    float s = 0.f;
                    #pragma unroll
                    for (int dd = 0; dd < D; ++dd) s = fmaf(qr[r][dd], kr[dd], s);
                    float e = EXP2(fmaf(s, scale2, tbp[r][-joff]));
                    lsum[r] += e;
                    #pragma unroll
                    for (int dd = 0; dd < D; ++dd) acc[r][dd] = fmaf(e, kr[D + dd], acc[r][dd]);
                }
            }
        };
        if constexpr (UNR == 2) {
            #pragma unroll 2
            for (int jg = 0; jg < TILE; jg += 4) group(jg);
        } else {
            for (int jg = 0; jg < TILE; jg += 4) group(jg);
        }
        if (NBUF > 1 && t + 2 < NT) {
            // all reads of buf[t&1] done (DS in-order) before DMA may overwrite it
            asm volatile("s_waitcnt lgkmcnt(0)" ::: "memory");
            stage(t & 1, t + 2);
            waitcnt_vm<3>();   // tile t+1 resident; tile t+2's 3 loads stay in flight
        } else if (NBUF > 1 && t + 1 < NT) {
            waitcnt_vm<0>();   // last tile: drain
        }
    }

    __syncthreads();
    #pragma unroll
    for (int r = 0; r < RPT; ++r) {
        float* cp = comb + (size_t)(wave * ROWS + lane + 64 * r) * CSTR;
        #pragma unroll
        for (int dd = 0; dd < D; ++dd) cp[dd] = acc[r][dd];
        cp[D] = lsum[r];
    }
    __syncthreads();
    if (tid < ROWS) {
        float af[D];
        #pragma unroll
        for (int dd = 0; dd < D; ++dd) af[dd] = 0.f;
        float lf = 0.f;
        #pragma unroll
        for (int wv = 0; wv < NW; ++wv) {
            const float* cp = comb + (size_t)(wv * ROWS + tid) * CSTR;
            #pragma unroll
            for (int dd = 0; dd < D; ++dd) af[dd] += cp[dd];
            lf += cp[D];
        }
        float inv = 1.0f / lf;
        int i = base + tid;
        #pragma unroll
        for (int dd = 0; dd < D; ++dd)
            o[((size_t)bh * D + dd) * N + i] = af[dd] * inv;  // O layout [bh][d][N]
    }
}

// ---------- L3 attention: one block per bh; KV+table staged in LDS; 8-wave j-split ----------
__global__ void __launch_bounds__(512) attn_small(const float* __restrict__ q,
                                                  const float* __restrict__ kv,
                                                  const float* __restrict__ table,
                                                  float* __restrict__ o, float scale2) {
    constexpr int D = 21, DP = 24, NN = 64;
    constexpr int CSTR = 23;
    __shared__ float smem[8 * NN * CSTR];  // 47104 B; comb overlays kvs/tb
    float* kvs = smem;
    float* tb = kvs + NN * 2 * DP;
    float* comb = smem;

    const int bh = blockIdx.x;     // 96 blocks
    const int h = bh % 3;
    const int tid = threadIdx.x;
    const int wave = __builtin_amdgcn_readfirstlane(tid >> 6);
    const int lane = tid & 63;

    {
        const float4* kvg = (const float4*)(kv + (size_t)bh * NN * 2 * DP);
        float4* kvs4 = (float4*)kvs;
        for (int t = tid; t < NN * 2 * DP / 4; t += 512) kvs4[t] = kvg[t];
        for (int t = tid; t < 225; t += 512) tb[t] = table[t * 3 + h] * scale2;
    }

    const int i = lane;
    const float* qg = q + ((size_t)bh * NN + i) * DP;
    float qr[D];
    #pragma unroll
    for (int dd = 0; dd < D; ++dd) qr[dd] = qg[dd];
    const int ibase = ((i >> 3) + 7) * 15 + (i & 7) + 7;
    __syncthreads();

    float acc[D];
    #pragma unroll
    for (int dd = 0; dd < D; ++dd) acc[dd] = 0.f;
    float lsum = 0.f;

    const int j0 = wave * 8;   // 8 waves x 8 js
    #pragma unroll
    for (int jj = 0; jj < 8; ++jj) {
        const int j = j0 + jj;
        float4 r4[12];
        const float4* rp = (const float4*)(kvs + j * 2 * DP);
        #pragma unroll
        for (int x = 0; x < 12; ++x) r4[x] = rp[x];
        const float* kr = (const float*)r4;
        const float* vr = kr + DP;
        const int joff = (j >> 3) * 15 + (j & 7);
        float s = 0.f;
        #pragma unroll
        for (int dd = 0; dd < D; ++dd) s = fmaf(qr[dd], kr[dd], s);
        float e = EXP2(fmaf(s, scale2, tb[ibase - joff]));
        lsum += e;
        #pragma unroll
        for (int dd = 0; dd < D; ++dd) acc[dd] = fmaf(e, vr[dd], acc[dd]);
    }

    __syncthreads();
    {
        float* cp = comb + (size_t)(wave * NN + lane) * CSTR;
        #pragma unroll
        for (int dd = 0; dd < D; ++dd) cp[dd] = acc[dd];
        cp[D] = lsum;
    }
    __syncthreads();
    if (tid < NN) {
        float af[D];
        #pragma unroll
        for (int dd = 0; dd < D; ++dd) af[dd] = 0.f;
        float lf = 0.f;
        #pragma unroll
        for (int wv = 0; wv < 8; ++wv) {
            const float* cp = comb + (size_t)(wv * NN + tid) * CSTR;
            #pragma unroll
            for (int dd = 0; dd < D; ++dd) af[dd] += cp[dd];
            lf += cp[D];
        }
        float inv = 1.0f / lf;
        #pragma unroll
        for (int dd = 0; dd < D; ++dd)
            o[((size_t)bh * D + dd) * NN + tid] = af[dd] * inv;
    }
}

// ---------- tail: outproj3 + global-avg-pool + classifier (3-way ILP over hh) ----------
__global__ void __launch_bounds__(256) tail(const float* __restrict__ o,
                                            const float* __restrict__ ow,
                                            const float* __restrict__ ob,
                                            const float* __restrict__ zin,
                                            const float* __restrict__ cw,
                                            const float* __restrict__ cb,
                                            float* __restrict__ out) {
    __shared__ float os[63 * 64];
    __shared__ float zt[64 * 65];
    __shared__ float p[64];
    const int b = blockIdx.x;
    const int tid = threadIdx.x;
    // stage o[b]: rows b*63..b*63+62 are contiguous (layout [bh][d][N], hd = hh*21+dd)
    for (int t = tid; t < 63 * 64; t += 256) os[t] = o[(size_t)(b * 63) * 64 + t];
    __syncthreads();
    for (int idx = tid; idx < 64 * 64; idx += 256) {
        int c = idx >> 6, n = idx & 63;
        const float* wp = ow + (size_t)c * 63;
        float v0 = 0.f, v1 = 0.f, v2 = 0.f;
        for (int dd = 0; dd < 21; ++dd) {
            v0 = fmaf(wp[dd * 3 + 0], os[(0  + dd) * 64 + n], v0);
            v1 = fmaf(wp[dd * 3 + 1], os[(21 + dd) * 64 + n], v1);
            v2 = fmaf(wp[dd * 3 + 2], os[(42 + dd) * 64 + n], v2);
        }
        zt[c * 65 + n] = ob[c] + zin[((size_t)(b * 64) + c) * 64 + n] + (v0 + v1) + v2;
    }
    __syncthreads();
    if (tid < 64) {
        float s = 0.f;
        #pragma unroll
        for (int n = 0; n < 64; ++n) s += zt[tid * 65 + n];
        s *= (1.0f / 64.0f);
        p[tid] = s;
        out[b * 64 + tid] = s;
    }
    __syncthreads();
    if (tid < 10) {
        float val = cb[tid];
        const float* wp = cw + (size_t)tid * 64;
        #pragma unroll
        for (int kk = 0; kk < 64; ++kk) val = fmaf(wp[kk], p[kk], val);
        out[2048 + b * 10 + tid] = val;
    }
}

extern "C" void kernel_launch(void* const* d_in, const int* in_sizes, int n_in,
                              void* d_out, int out_size, void* d_ws, size_t ws_size,
                              hipStream_t stream) {
    float* ws = (float*)d_ws;
    float* Zc1 = ws;                 // conv1 z (524288) / later conv3 z (131072)
    float* Zc2 = Zc1 + 524288;       // conv2 z (262144)
    float* Q   = Zc2 + 262144;       // 786432 (96*1024*8 max)
    float* KV  = Q + 786432;         // 1572864 region (L1 packed uses 96*1024*12)
    float* O   = KV + 1572864;       // 491520 (96*1024*5 max)

    float* out = (float*)d_out;

    // ===== layer 1: Cin=1 H64->32, dim=16, inner=15, d=5 (q pad 8, kv stride 12), N=1024 =====
    conv_qkv<1, 64, 16, 32, 15, 8, 12, 5, 32, 512><<<32 * 32, 512, 0, stream>>>(
        (const float*)d_in[0], (const float*)d_in[1], (const float*)d_in[2],
        (const float*)d_in[3], (const float*)d_in[4], Zc1, Q, KV);
    // R15-best config for L1: UNR=1 (4-j cadence); SALU wave pin; RPT=2, NW=4, TILE=64
    attn_big<5, 8, 12, 2, 64, 4, 2, 1><<<96 * 8, 256, 40464, stream>>>(
        Q, KV, (const float*)d_in[7], O, 1024, 5, 3969, SC5);

    // ===== layer 2 (fused outproj1 + conv2 + qkv2): dim=32, d=10 (q pad 12, kv stride 20), N=256 =====
    fused_oc<16, 15, 5, 32, 32, 16, 30, 12, 20, 10, 16, 512><<<32 * 16, 512, 0, stream>>>(
        O, (const float*)d_in[5], (const float*)d_in[6], Zc1,
        (const float*)d_in[8], (const float*)d_in[9],
        (const float*)d_in[10], (const float*)d_in[11], Zc2, Q, KV);
    // R16-best config for L2: UNR=2 (8-j flattened body); NW=8, RPT=1, TILE=32, NBUF=1
    attn_big<10, 12, 20, 1, 32, 8, 1, 2><<<96 * 4, 512, 26624, stream>>>(
        Q, KV, (const float*)d_in[14], O, 256, 4, 961, SC10);

    // ===== layer 3 (fused outproj2 + conv3 + qkv3): dim=64, d=21 (DP=24, kv interleaved 48) =====
    fused_oc<32, 30, 10, 16, 64, 8, 63, 24, 48, 24, 8, 512><<<32 * 8, 512, 0, stream>>>(
        O, (const float*)d_in[12], (const float*)d_in[13], Zc2,
        (const float*)d_in[15], (const float*)d_in[16],
        (const float*)d_in[17], (const float*)d_in[18], Zc1, Q, KV);
    attn_small<<<96, 512, 0, stream>>>(Q, KV, (const float*)d_in[21], O, SC21);

    // ===== head =====
    tail<<<32, 256, 0, stream>>>(
        O, (const float*)d_in[19], (const float*)d_in[20], Zc1,
        (const float*)d_in[22], (const float*)d_in[23], out);
}